// Round 6
// baseline (310.426 us; speedup 1.0000x reference)
//
#include <hip/hip_runtime.h>
#include <math.h>

#define PI_F 3.14159265358979323846f

// Odd strides -> conflict-free LDS banking for the radix-8 FFT access patterns.
#define RST 69   // real (float) row stride, was 65
#define CS  67   // complex stage stride (float2), was 66
#define KS  35   // ky-layout stride (float2), was 34
#define NBUF 2240

typedef __attribute__((ext_vector_type(8))) short short8;
typedef __attribute__((ext_vector_type(4))) float f32x4;
typedef __attribute__((ext_vector_type(4))) unsigned short u16x4;
typedef __attribute__((ext_vector_type(8))) unsigned short u16x8;

static __device__ __forceinline__ unsigned short f2bf(float x) {
    unsigned u = __float_as_uint(x);
    unsigned r = (u + 0x7FFF + ((u >> 16) & 1)) >> 16;
    return (unsigned short)r;
}
static __device__ __forceinline__ float bf2f(unsigned short u) {
    return __uint_as_float(((unsigned)u) << 16);
}

static __device__ __forceinline__ float2 cadd(float2 a, float2 b) { return make_float2(a.x + b.x, a.y + b.y); }
static __device__ __forceinline__ float2 csub(float2 a, float2 b) { return make_float2(a.x - b.x, a.y - b.y); }
static __device__ __forceinline__ float2 cmul(float2 a, float2 b) { return make_float2(a.x * b.x - a.y * b.y, a.x * b.y + a.y * b.x); }
static __device__ __forceinline__ float2 cmulc(float2 a, float2 b) { return make_float2(a.x * b.x + a.y * b.y, a.y * b.x - a.x * b.y); }

template <int S>
static __device__ __forceinline__ void dft8(float2* z) {
    const float RT = 0.70710678118654752440f;
    float2 ee0 = cadd(z[0], z[4]), ee1 = csub(z[0], z[4]);
    float2 eo0 = cadd(z[2], z[6]), eo1 = csub(z[2], z[6]);
    float2 oe0 = cadd(z[1], z[5]), oe1 = csub(z[1], z[5]);
    float2 oo0 = cadd(z[3], z[7]), oo1 = csub(z[3], z[7]);
    float2 ieo1 = make_float2(-S * eo1.y, S * eo1.x);
    float2 ioo1 = make_float2(-S * oo1.y, S * oo1.x);
    float2 E0 = cadd(ee0, eo0), E2 = csub(ee0, eo0);
    float2 E1 = cadd(ee1, ieo1), E3 = csub(ee1, ieo1);
    float2 O0 = cadd(oe0, oo0), O2 = csub(oe0, oo0);
    float2 O1 = cadd(oe1, ioo1), O3 = csub(oe1, ioo1);
    float2 w1O1 = make_float2(RT * (O1.x - S * O1.y), RT * (S * O1.x + O1.y));
    float2 w3O3 = make_float2(RT * (-O3.x - S * O3.y), RT * (S * O3.x - O3.y));
    float2 iO2  = make_float2(-S * O2.y, S * O2.x);
    z[0] = cadd(E0, O0);   z[4] = csub(E0, O0);
    z[1] = cadd(E1, w1O1); z[5] = csub(E1, w1O1);
    z[2] = cadd(E2, iO2);  z[6] = csub(E2, iO2);
    z[3] = cadd(E3, w3O3); z[7] = csub(E3, w3O3);
}

// ---------------------------------------------------------------- k_params
__global__ __launch_bounds__(256) void k_params(const float* __restrict__ stats,
                                                const float* __restrict__ gw,
                                                const float* __restrict__ gb,
                                                const float* __restrict__ dts,
                                                float2* __restrict__ A,
                                                float2* __restrict__ Xt) {
    int idx = blockIdx.x * 256 + threadIdx.x;
    int c = idx & 127;
    int bt = idx >> 7;
    const float* st = stats + bt * 128;
    float nu = gb[c], om = gb[c + 128];
    for (int k = 0; k < 128; ++k) {
        float s = st[k];
        nu += s * gw[k * 256 + c];
        om += s * gw[k * 256 + c + 128];
    }
    float dt = dts[bt];
    float lre = -fabsf(nu);
    float lim = om;
    float mag = sqrtf(lre * lre + lim * lim);
    float er = expf(lre * dt);
    float sn, cs;
    sincosf(lim * dt, &sn, &cs);
    float2 Av = make_float2(er * cs, er * sn);
    float2 X;
    if (mag < 1e-6f) {
        X = make_float2(dt, 0.f);
    } else {
        float ar = Av.x - 1.f, ai = Av.y;
        float inv = 1.f / (mag * mag);
        X = make_float2((ar * lre + ai * lim) * inv, (ai * lre - ar * lim) * inv);
    }
    A[idx] = Av;
    Xt[idx] = X;
}

// ---------------------------------------------------------------- k_rfft2s (radix-8, fused stats, bf16 spectra out)
__global__ __launch_bounds__(256) void k_rfft2s(const float* __restrict__ xin,
                                                unsigned* __restrict__ Sb,
                                                float* __restrict__ stats) {
    int img = blockIdx.x, tid = threadIdx.x;
    __shared__ float2 bufA[NBUF], bufB[NBUF], bufC[NBUF], twl[64];
    __shared__ float red[4];
    float* Af = (float*)bufA;
    if (tid < 64) {
        float sn, cs;
        sincosf(-(2.0f * PI_F / 64.0f) * (float)tid, &sn, &cs);
        twl[tid] = make_float2(cs, sn);
    }
    const float* xp = xin + (size_t)img * 4096;
    float ssum = 0.f;
    for (int i4 = tid; i4 < 1024; i4 += 256) {
        float4 v = ((const float4*)xp)[i4];
        ssum += v.x + v.y + v.z + v.w;
        int r = i4 >> 4, w = (i4 & 15) << 2;
        float* d = Af + r * RST + w;
        d[0] = v.x; d[1] = v.y; d[2] = v.z; d[3] = v.w;
    }
    for (int off = 32; off > 0; off >>= 1) ssum += __shfl_xor(ssum, off, 64);
    if ((tid & 63) == 0) red[tid >> 6] = ssum;
    __syncthreads();
    if (tid == 0) stats[img] = (red[0] + red[1] + red[2] + red[3]) * (1.0f / 4096.0f);

    // P2: row FFT stage A (rows packed in pairs).
    {
        int j = tid >> 3, b = tid & 7;
        const float* p0 = Af + (2 * j) * RST + b;
        const float* p1 = p0 + RST;
        float2 z[8];
#pragma unroll
        for (int a = 0; a < 8; ++a) z[a] = make_float2(p0[8 * a], p1[8 * a]);
        dft8<-1>(z);
#pragma unroll
        for (int c = 0; c < 8; ++c) bufB[j * CS + c * 8 + b] = cmul(z[c], twl[(b * c) & 63]);
    }
    __syncthreads();

    // P3: row FFT stage B.
    {
        int j = tid >> 3, c = tid & 7;
        float2 z[8];
#pragma unroll
        for (int b = 0; b < 8; ++b) z[b] = bufB[j * CS + c * 8 + b];
        dft8<-1>(z);
#pragma unroll
        for (int d = 0; d < 8; ++d) bufC[j * CS + c + 8 * d] = z[d];
    }
    __syncthreads();

    // P4: Hermitian unpack -> transposed.
    for (int idx = tid; idx < 1056; idx += 256) {
        int j = idx / 33, k = idx - j * 33;
        float2 zk = bufC[j * CS + k];
        float2 zm = bufC[j * CS + ((64 - k) & 63)];
        bufA[k * CS + 2 * j]     = make_float2((zk.x + zm.x) * 0.5f, (zk.y - zm.y) * 0.5f);
        bufA[k * CS + 2 * j + 1] = make_float2((zk.y + zm.y) * 0.5f, (zm.x - zk.x) * 0.5f);
    }
    __syncthreads();

    // P5: column FFT stage A.
    auto colA = [&](int kx, int b) {
        float2 z[8];
#pragma unroll
        for (int a = 0; a < 8; ++a) z[a] = bufA[kx * CS + 8 * a + b];
        dft8<-1>(z);
#pragma unroll
        for (int c = 0; c < 8; ++c) bufB[kx * CS + c * 8 + b] = cmul(z[c], twl[(b * c) & 63]);
    };
    colA(tid >> 3, tid & 7);
    if (tid < 8) colA(32, tid);
    __syncthreads();

    // P6: column FFT stage B -> C[ky*KS+kx].
    auto colB = [&](int kx, int c) {
        float2 z[8];
#pragma unroll
        for (int b = 0; b < 8; ++b) z[b] = bufB[kx * CS + c * 8 + b];
        dft8<-1>(z);
#pragma unroll
        for (int d = 0; d < 8; ++d) bufC[(c + 8 * d) * KS + kx] = z[d];
    };
    colB(tid >> 3, tid & 7);
    if (tid < 8) colB(32, tid);
    __syncthreads();

    // P7: ortho scale, bf16 pack, coalesced store.
    unsigned* op = Sb + (size_t)img * 2112;
    for (int i = tid; i < 2112; i += 256) {
        int ky = i / 33, kx = i - ky * 33;
        float2 v = bufC[ky * KS + kx];
        unsigned lo = f2bf(v.x * (1.0f / 64.0f));
        unsigned hi = f2bf(v.y * (1.0f / 64.0f));
        op[i] = lo | (hi << 16);
    }
}

// ---------------------------------------------------------------- k_scan (bf16 spectra, fused Xterm)
__global__ __launch_bounds__(256) void k_scan(unsigned* __restrict__ Sb,
                                              const float2* __restrict__ A,
                                              const float2* __restrict__ Xt) {
    int tid = blockIdx.x * 256 + threadIdx.x;
    int spec = tid % 2112;
    int c = (tid / 2112) & 127;
    int b = tid / (2112 * 128);
    float2 h = make_float2(0.f, 0.f);
    for (int t = 0; t < 16; ++t) {
        int bt = b * 16 + t;
        float2 a = A[bt * 128 + c];
        float2 xt = Xt[bt * 128 + c];
        size_t off = ((size_t)(bt * 128 + c)) * 2112 + spec;
        unsigned v = Sb[off];
        float2 xr = make_float2(bf2f((unsigned short)(v & 0xffff)), bf2f((unsigned short)(v >> 16)));
        float2 x = cmul(xr, xt);
        float hr = a.x * h.x - a.y * h.y + x.x;
        float hi = a.x * h.y + a.y * h.x + x.y;
        h = make_float2(hr, hi);
        Sb[off] = (unsigned)f2bf(hr) | ((unsigned)f2bf(hi) << 16);
    }
}

// ---------------------------------------------------------------- k_irfft2b (radix-8, bf16 in/out)
__global__ __launch_bounds__(256) void k_irfft2b(const unsigned* __restrict__ Sb,
                                                 unsigned short* __restrict__ hb) {
    int img = blockIdx.x, tid = threadIdx.x;
    __shared__ float2 bufA[NBUF], bufB[NBUF], bufC[NBUF], twl[64];
    float* Cf = (float*)bufC;
    if (tid < 64) {
        float sn, cs;
        sincosf(-(2.0f * PI_F / 64.0f) * (float)tid, &sn, &cs);
        twl[tid] = make_float2(cs, sn);
    }
    const unsigned* ip = Sb + (size_t)img * 2112;
    for (int i = tid; i < 2112; i += 256) {
        int ky = i / 33, kx = i - ky * 33;
        unsigned v = ip[i];
        bufA[ky * KS + kx] = make_float2(bf2f((unsigned short)(v & 0xffff)), bf2f((unsigned short)(v >> 16)));
    }
    __syncthreads();

    auto colA = [&](int kx, int b) {
        float2 z[8];
#pragma unroll
        for (int a = 0; a < 8; ++a) z[a] = bufA[(8 * a + b) * KS + kx];
        dft8<1>(z);
#pragma unroll
        for (int c = 0; c < 8; ++c) bufB[kx * CS + c * 8 + b] = cmulc(z[c], twl[(b * c) & 63]);
    };
    colA(tid >> 3, tid & 7);
    if (tid < 8) colA(32, tid);
    __syncthreads();

    auto colB = [&](int kx, int c) {
        float2 z[8];
#pragma unroll
        for (int b = 0; b < 8; ++b) z[b] = bufB[kx * CS + c * 8 + b];
        dft8<1>(z);
#pragma unroll
        for (int d = 0; d < 8; ++d) bufC[(c + 8 * d) * KS + kx] = z[d];
    };
    colB(tid >> 3, tid & 7);
    if (tid < 8) colB(32, tid);
    __syncthreads();

    // pack row pairs; irfft semantics: drop imag of DC/Nyquist kx bins.
    for (int idx = tid; idx < 2048; idx += 256) {
        int j = idx >> 6, k = idx & 63;
        int kk = (k <= 32) ? k : 64 - k;
        float2 t0 = bufC[(2 * j) * KS + kk];
        float2 t1 = bufC[(2 * j + 1) * KS + kk];
        if (kk == 0 || kk == 32) { t0.y = 0.f; t1.y = 0.f; }
        float sgn = (k <= 32) ? 1.f : -1.f;
        t0.y *= sgn; t1.y *= sgn;
        bufA[j * CS + k] = make_float2(t0.x - t1.y, t0.y + t1.x);
    }
    __syncthreads();

    {
        int j = tid >> 3, b = tid & 7;
        float2 z[8];
#pragma unroll
        for (int a = 0; a < 8; ++a) z[a] = bufA[j * CS + 8 * a + b];
        dft8<1>(z);
#pragma unroll
        for (int c = 0; c < 8; ++c) bufB[j * CS + c * 8 + b] = cmulc(z[c], twl[(b * c) & 63]);
    }
    __syncthreads();

    {
        int j = tid >> 3, c = tid & 7;
        float2 z[8];
#pragma unroll
        for (int b = 0; b < 8; ++b) z[b] = bufB[j * CS + c * 8 + b];
        dft8<1>(z);
#pragma unroll
        for (int d = 0; d < 8; ++d) {
            int w = c + 8 * d;
            Cf[(2 * j) * RST + w]     = z[d].x;
            Cf[(2 * j + 1) * RST + w] = z[d].y;
        }
    }
    __syncthreads();

    unsigned short* op = hb + (size_t)img * 4096;
    for (int i4 = tid; i4 < 1024; i4 += 256) {
        int r = i4 >> 4, w = (i4 & 15) << 2;
        const float* s = Cf + r * RST + w;
        u16x4 o;
        o[0] = f2bf(s[0] * (1.0f / 64.0f));
        o[1] = f2bf(s[1] * (1.0f / 64.0f));
        o[2] = f2bf(s[2] * (1.0f / 64.0f));
        o[3] = f2bf(s[3] * (1.0f / 64.0f));
        ((u16x4*)op)[i4] = o;
    }
}

// ---------------------------------------------------------------- k_wprep
__global__ __launch_bounds__(256) void k_wprep(const float* __restrict__ cwa,
                                               const float* __restrict__ cwb,
                                               unsigned short* __restrict__ Wb) {
    int idx = blockIdx.x * 256 + threadIdx.x;   // 147456 total
    int kl = idx & 31;
    int m = (idx >> 5) & 127;
    int tcb = idx >> 12;          // 0..35
    int cb = tcb & 3, t = tcb >> 2;
    int ci = cb * 32 + kl;
    int mm = m & 63, cc = ci & 63;
    float w;
    if (m < 64) w = (ci < 64) ? cwa[(mm * 64 + cc) * 9 + t] : -cwb[(mm * 64 + cc) * 9 + t];
    else        w = (ci < 64) ? cwb[(mm * 64 + cc) * 9 + t] :  cwa[(mm * 64 + cc) * 9 + t];
    if (m == ci && t == 4) w += 1.0f;   // residual folded into center tap
    Wb[idx] = f2bf(w);
}

// ---------------------------------------------------------------- k_conv_mfma (bf16 in, bf16 out)
__global__ __launch_bounds__(256, 2) void k_conv_mfma(const unsigned short* __restrict__ hb,
                                                      const unsigned short* __restrict__ Wb,
                                                      const float* __restrict__ cba,
                                                      const float* __restrict__ cbb,
                                                      unsigned short* __restrict__ uout) {
    __shared__ __align__(16) char smem[65536];
    int f = blockIdx.y;
    int r0 = blockIdx.x * 2;
    int tid = threadIdx.x;
    const unsigned short* base = hb + (size_t)f * 524288;

    for (int j = tid; j < 4096; j += 256) {
        int row = j >> 10;
        int cig = (j >> 6) & 15;
        int col = j & 63;
        int gr = r0 - 1 + row;
        short8 v = (short8)0;
        if ((unsigned)gr < 64u) {
            const unsigned short* p = base + (size_t)(cig * 8) * 4096 + gr * 64 + col;
#pragma unroll
            for (int e = 0; e < 8; ++e) v[e] = (short)p[(size_t)e * 4096];
        }
        int byteoff = ((row * 64 + col) << 8) + ((cig ^ (col & 15)) << 4);
        *(short8*)(smem + byteoff) = v;
    }
    __syncthreads();

    int wid = tid >> 6, lane = tid & 63;
    int lhi = lane >> 4, llo = lane & 15;
    int row_off = wid & 1;
    int mbase = (wid >> 1) * 64;

    f32x4 acc[4][4];
#pragma unroll
    for (int mf = 0; mf < 4; ++mf)
#pragma unroll
        for (int nf = 0; nf < 4; ++nf) acc[mf][nf] = (f32x4)0.f;

    for (int t = 0; t < 9; ++t) {
        int dy = t / 3 - 1, dx = t % 3 - 1;
        int prow = row_off + 1 + dy;
#pragma unroll
        for (int cb = 0; cb < 4; ++cb) {
            short8 a[4];
            const unsigned short* wp = Wb + ((size_t)((t * 4 + cb) * 128 + mbase + llo)) * 32 + lhi * 8;
#pragma unroll
            for (int mf = 0; mf < 4; ++mf) a[mf] = *(const short8*)(wp + mf * 16 * 32);
            short8 b[4];
            int slot = cb * 4 + lhi;
#pragma unroll
            for (int nf = 0; nf < 4; ++nf) {
                int c = nf * 16 + llo;
                int cdx = c + dx;
                bool valid = ((unsigned)cdx < 64u);
                int cr = valid ? cdx : c;
                int byteoff = ((prow * 64 + cr) << 8) + ((slot ^ (cr & 15)) << 4);
                short8 bb = *(const short8*)(smem + byteoff);
                b[nf] = valid ? bb : (short8)0;
            }
#pragma unroll
            for (int mf = 0; mf < 4; ++mf)
#pragma unroll
                for (int nf = 0; nf < 4; ++nf)
                    acc[mf][nf] = __builtin_amdgcn_mfma_f32_16x16x32_bf16(a[mf], b[nf], acc[mf][nf], 0, 0, 0);
        }
    }

    int grow = r0 + row_off;
#pragma unroll
    for (int mf = 0; mf < 4; ++mf) {
#pragma unroll
        for (int r = 0; r < 4; ++r) {
            int co = mbase + mf * 16 + lhi * 4 + r;
            float bias = (co < 64) ? cba[co] : cbb[co - 64];
            unsigned short* op = uout + ((size_t)f * 128 + co) * 4096 + (size_t)grow * 64;
#pragma unroll
            for (int nf = 0; nf < 4; ++nf)
                op[nf * 16 + llo] = f2bf(acc[mf][nf][r] + bias);
        }
    }
}

// ---------------------------------------------------------------- k_helm (fused rfft2 + project + irfft2 + GN partials)
// Block = (frame f, channel c in 0..63). Handles images (f, c) and (f, c+64). bf16 in/out.
__global__ __launch_bounds__(256) void k_helm(const unsigned short* __restrict__ uin,
                                              unsigned short* __restrict__ uo,
                                              float* __restrict__ partials) {
    int bid = blockIdx.x;
    int f = bid >> 6, c = bid & 63;
    int tid = threadIdx.x;
    __shared__ float2 W0[NBUF], W1[NBUF], SP[NBUF], twl[64];
    __shared__ float red[4];
    if (tid < 64) {
        float sn, cs;
        sincosf(-(2.0f * PI_F / 64.0f) * (float)tid, &sn, &cs);
        twl[tid] = make_float2(cs, sn);
    }

    auto loadimg = [&](const unsigned short* xp, float2* W) {
        float* Wf = (float*)W;
        for (int i4 = tid; i4 < 1024; i4 += 256) {
            u16x4 v = ((const u16x4*)xp)[i4];
            int r = i4 >> 4, w = (i4 & 15) << 2;
            float* d = Wf + r * RST + w;
            d[0] = bf2f(v[0]); d[1] = bf2f(v[1]); d[2] = bf2f(v[2]); d[3] = bf2f(v[3]);
        }
    };
    auto fwdP2 = [&](const float2* src, float2* dst) {
        const float* Af = (const float*)src;
        int j = tid >> 3, b = tid & 7;
        const float* p0 = Af + (2 * j) * RST + b;
        const float* p1 = p0 + RST;
        float2 z[8];
#pragma unroll
        for (int a = 0; a < 8; ++a) z[a] = make_float2(p0[8 * a], p1[8 * a]);
        dft8<-1>(z);
#pragma unroll
        for (int cc = 0; cc < 8; ++cc) dst[j * CS + cc * 8 + b] = cmul(z[cc], twl[(b * cc) & 63]);
    };
    auto fwdP3 = [&](const float2* src, float2* dst) {
        int j = tid >> 3, cc = tid & 7;
        float2 z[8];
#pragma unroll
        for (int b = 0; b < 8; ++b) z[b] = src[j * CS + cc * 8 + b];
        dft8<-1>(z);
#pragma unroll
        for (int d = 0; d < 8; ++d) dst[j * CS + cc + 8 * d] = z[d];
    };
    auto fwdP4 = [&](const float2* src, float2* dst) {
        for (int idx = tid; idx < 1056; idx += 256) {
            int j = idx / 33, k = idx - j * 33;
            float2 zk = src[j * CS + k];
            float2 zm = src[j * CS + ((64 - k) & 63)];
            dst[k * CS + 2 * j]     = make_float2((zk.x + zm.x) * 0.5f, (zk.y - zm.y) * 0.5f);
            dst[k * CS + 2 * j + 1] = make_float2((zk.y + zm.y) * 0.5f, (zm.x - zk.x) * 0.5f);
        }
    };
    auto fwdP5 = [&](const float2* src, float2* dst) {
        auto body = [&](int kx, int b) {
            float2 z[8];
#pragma unroll
            for (int a = 0; a < 8; ++a) z[a] = src[kx * CS + 8 * a + b];
            dft8<-1>(z);
#pragma unroll
            for (int cc = 0; cc < 8; ++cc) dst[kx * CS + cc * 8 + b] = cmul(z[cc], twl[(b * cc) & 63]);
        };
        body(tid >> 3, tid & 7);
        if (tid < 8) body(32, tid);
    };
    auto fwdP6 = [&](const float2* src, float2* dst) {
        auto body = [&](int kx, int cc) {
            float2 z[8];
#pragma unroll
            for (int b = 0; b < 8; ++b) z[b] = src[kx * CS + cc * 8 + b];
            dft8<-1>(z);
#pragma unroll
            for (int d = 0; d < 8; ++d) dst[(cc + 8 * d) * KS + kx] = z[d];
        };
        body(tid >> 3, tid & 7);
        if (tid < 8) body(32, tid);
    };
    auto invA = [&](const float2* src, float2* dst) {
        auto body = [&](int kx, int b) {
            float2 z[8];
#pragma unroll
            for (int a = 0; a < 8; ++a) z[a] = src[(8 * a + b) * KS + kx];
            dft8<1>(z);
#pragma unroll
            for (int cc = 0; cc < 8; ++cc) dst[kx * CS + cc * 8 + b] = cmulc(z[cc], twl[(b * cc) & 63]);
        };
        body(tid >> 3, tid & 7);
        if (tid < 8) body(32, tid);
    };
    auto invB = [&](const float2* src, float2* dst) {
        auto body = [&](int kx, int cc) {
            float2 z[8];
#pragma unroll
            for (int b = 0; b < 8; ++b) z[b] = src[kx * CS + cc * 8 + b];
            dft8<1>(z);
#pragma unroll
            for (int d = 0; d < 8; ++d) dst[(cc + 8 * d) * KS + kx] = z[d];
        };
        body(tid >> 3, tid & 7);
        if (tid < 8) body(32, tid);
    };
    auto invP4 = [&](const float2* src, float2* dst) {
        for (int idx = tid; idx < 2048; idx += 256) {
            int j = idx >> 6, k = idx & 63;
            int kk = (k <= 32) ? k : 64 - k;
            float2 t0 = src[(2 * j) * KS + kk];
            float2 t1 = src[(2 * j + 1) * KS + kk];
            if (kk == 0 || kk == 32) { t0.y = 0.f; t1.y = 0.f; }
            float sgn = (k <= 32) ? 1.f : -1.f;
            t0.y *= sgn; t1.y *= sgn;
            dst[j * CS + k] = make_float2(t0.x - t1.y, t0.y + t1.x);
        }
    };
    auto invP5 = [&](const float2* src, float2* dst) {
        int j = tid >> 3, b = tid & 7;
        float2 z[8];
#pragma unroll
        for (int a = 0; a < 8; ++a) z[a] = src[j * CS + 8 * a + b];
        dft8<1>(z);
#pragma unroll
        for (int cc = 0; cc < 8; ++cc) dst[j * CS + cc * 8 + b] = cmulc(z[cc], twl[(b * cc) & 63]);
    };
    auto invP6 = [&](const float2* src, float2* dst) {
        float* Df = (float*)dst;
        int j = tid >> 3, cc = tid & 7;
        float2 z[8];
#pragma unroll
        for (int b = 0; b < 8; ++b) z[b] = src[j * CS + cc * 8 + b];
        dft8<1>(z);
#pragma unroll
        for (int d = 0; d < 8; ++d) {
            int w = cc + 8 * d;
            Df[(2 * j) * RST + w]     = z[d].x;
            Df[(2 * j + 1) * RST + w] = z[d].y;
        }
    };
    auto writeimg = [&](const float2* W, unsigned short* op, int pslot) {
        const float* Wf = (const float*)W;
        float s = 0.f, q = 0.f;
        for (int i4 = tid; i4 < 1024; i4 += 256) {
            int r = i4 >> 4, w = (i4 & 15) << 2;
            const float* sp = Wf + r * RST + w;
            float a0 = sp[0] * (1.0f / 4096.0f), a1 = sp[1] * (1.0f / 4096.0f);
            float a2 = sp[2] * (1.0f / 4096.0f), a3 = sp[3] * (1.0f / 4096.0f);
            s += a0 + a1 + a2 + a3;
            q += a0 * a0 + a1 * a1 + a2 * a2 + a3 * a3;
            u16x4 o; o[0] = f2bf(a0); o[1] = f2bf(a1); o[2] = f2bf(a2); o[3] = f2bf(a3);
            ((u16x4*)op)[i4] = o;
        }
        for (int off = 32; off > 0; off >>= 1) {
            s += __shfl_xor(s, off, 64);
            q += __shfl_xor(q, off, 64);
        }
        __syncthreads();
        if ((tid & 63) == 0) { red[tid >> 6] = s; }
        __syncthreads();
        float stot = (tid == 0) ? (red[0] + red[1] + red[2] + red[3]) : 0.f;
        __syncthreads();
        if ((tid & 63) == 0) { red[tid >> 6] = q; }
        __syncthreads();
        if (tid == 0) {
            float qtot = red[0] + red[1] + red[2] + red[3];
            float* pp = partials + ((size_t)f * 64 + c) * 4 + pslot * 2;
            pp[0] = stot;
            pp[1] = qtot;
        }
    };

    const unsigned short* u0 = uin + ((size_t)f * 128 + c) * 4096;
    const unsigned short* u1 = uin + ((size_t)f * 128 + 64 + c) * 4096;
    unsigned short* o0 = uo + ((size_t)f * 128 + c) * 4096;
    unsigned short* o1 = uo + ((size_t)f * 128 + 64 + c) * 4096;

    // forward image0 -> SP
    loadimg(u0, W0);            __syncthreads();
    fwdP2(W0, W1);              __syncthreads();
    fwdP3(W1, W0);              __syncthreads();
    fwdP4(W0, W1);              __syncthreads();
    fwdP5(W1, W0);              __syncthreads();
    fwdP6(W0, SP);              __syncthreads();
    // forward image1 -> W1
    loadimg(u1, W0);            __syncthreads();
    fwdP2(W0, W1);              __syncthreads();
    fwdP3(W1, W0);              __syncthreads();
    fwdP4(W0, W1);              __syncthreads();
    fwdP5(W1, W0);              __syncthreads();
    fwdP6(W0, W1);              __syncthreads();

    // Helmholtz projection: SP = vx spectrum, W1 = vy spectrum (KS-layout).
    for (int i = tid; i < 64 * KS; i += 256) {
        int ky = i / KS, kx = i - ky * KS;
        if (kx > 32) continue;
        float kxv = (float)kx * (1.0f / 64.0f);
        float kyv = (float)(ky < 32 ? ky : ky - 64) * (1.0f / 64.0f);
        float k2 = kxv * kxv + kyv * kyv;
        if (k2 > 0.f) {
            float2 vx = SP[i], vy = W1[i];
            float inv = 1.0f / k2;
            float pr = (kxv * vx.x + kyv * vy.x) * inv;
            float pi = (kxv * vx.y + kyv * vy.y) * inv;
            SP[i] = make_float2(vx.x - kxv * pr, vx.y - kxv * pi);
            W1[i] = make_float2(vy.x - kyv * pr, vy.y - kyv * pi);
        }
    }
    __syncthreads();

    // inverse image0: SP -> real
    invA(SP, W0);               __syncthreads();
    invB(W0, SP);               __syncthreads();
    invP4(SP, W0);              __syncthreads();
    invP5(W0, SP);              __syncthreads();
    invP6(SP, W0);              __syncthreads();
    writeimg(W0, o0, 0);        __syncthreads();
    // inverse image1: W1 -> real
    invA(W1, W0);               __syncthreads();
    invB(W0, W1);               __syncthreads();
    invP4(W1, W0);              __syncthreads();
    invP5(W0, W1);              __syncthreads();
    invP6(W1, W0);              __syncthreads();
    writeimg(W0, o1, 1);
}

// ---------------------------------------------------------------- k_gnfin
__global__ __launch_bounds__(128) void k_gnfin(const float* __restrict__ partials,
                                               float2* __restrict__ gs) {
    int i = threadIdx.x;          // 0..127 = f*4 + g
    int f = i >> 2, g = i & 3;
    const float4* p4 = (const float4*)partials;
    float s = 0.f, q = 0.f;
    if (g < 2) {
        for (int cc = 0; cc < 32; ++cc) {
            float4 p = p4[f * 64 + g * 32 + cc];
            s += p.x; q += p.y;
        }
    } else {
        for (int cc = 0; cc < 32; ++cc) {
            float4 p = p4[f * 64 + (g - 2) * 32 + cc];
            s += p.z; q += p.w;
        }
    }
    float mu = s * (1.0f / 131072.0f);
    float var = q * (1.0f / 131072.0f) - mu * mu;
    gs[i] = make_float2(mu, rsqrtf(var + 1e-5f));
}

// ---------------------------------------------------------------- k_gnapply (bf16 in, fp32 out)
__global__ __launch_bounds__(256) void k_gnapply(const unsigned short* __restrict__ u,
                                                 const float2* __restrict__ gs,
                                                 const float* __restrict__ gnw,
                                                 const float* __restrict__ gnb,
                                                 float* __restrict__ out) {
    size_t i8 = (size_t)blockIdx.x * 256 + threadIdx.x;   // 2,097,152 exact
    u16x8 v = ((const u16x8*)u)[i8];
    int cl = (int)(i8 >> 9);      // f*128 + c
    int c = cl & 127;
    int fg = cl >> 5;             // f*4 + g
    float2 ms = gs[fg];
    float sc = ms.y * gnw[c];
    float sh = gnb[c] - ms.x * sc;
    float4 r0, r1;
    r0.x = bf2f(v[0]) * sc + sh; r0.y = bf2f(v[1]) * sc + sh;
    r0.z = bf2f(v[2]) * sc + sh; r0.w = bf2f(v[3]) * sc + sh;
    r1.x = bf2f(v[4]) * sc + sh; r1.y = bf2f(v[5]) * sc + sh;
    r1.z = bf2f(v[6]) * sc + sh; r1.w = bf2f(v[7]) * sc + sh;
    ((float4*)out)[i8 * 2]     = r0;
    ((float4*)out)[i8 * 2 + 1] = r1;
}

// ---------------------------------------------------------------- launch
extern "C" void kernel_launch(void* const* d_in, const int* in_sizes, int n_in,
                              void* d_out, int out_size, void* d_ws, size_t ws_size,
                              hipStream_t stream) {
    (void)in_sizes; (void)n_in; (void)out_size; (void)ws_size;
    const float* x   = (const float*)d_in[0];
    const float* dts = (const float*)d_in[1];
    const float* gw  = (const float*)d_in[2];
    const float* gb  = (const float*)d_in[3];
    const float* cwa = (const float*)d_in[4];
    const float* cwb = (const float*)d_in[5];
    const float* cba = (const float*)d_in[6];
    const float* cbb = (const float*)d_in[7];
    const float* gnw = (const float*)d_in[8];
    const float* gnb = (const float*)d_in[9];
    float* out = (float*)d_out;
    char* ws = (char*)d_ws;

    unsigned*       Sb  = (unsigned*)ws;                       // 34,603,008 B (bf16 spectra)
    unsigned short* Hb  = (unsigned short*)(ws + 34603008);    // 33,554,432 B (bf16 h)
    unsigned short* Ub  = (unsigned short*)(ws + 68157440);    // 33,554,432 B (bf16 u)
    unsigned short* H1b = (unsigned short*)(ws + 101711872);   // 33,554,432 B (bf16 helm out)
    float*  stats    = (float*)(ws + 135266304);               // 16,384 B
    float2* A        = (float2*)(ws + 135282688);              // 32,768 B
    float2* Xt       = (float2*)(ws + 135315456);              // 32,768 B
    float2* gs       = (float2*)(ws + 135348224);              // 1,024 B
    float*  partials = (float*)(ws + 135349248);               // 32,768 B
    unsigned short* Wb = (unsigned short*)ws;                  // aliases Sb (dead after irfft2b)

    k_rfft2s<<<4096, 256, 0, stream>>>(x, Sb, stats);
    k_params<<<16, 256, 0, stream>>>(stats, gw, gb, dts, A, Xt);
    k_scan<<<2112, 256, 0, stream>>>(Sb, A, Xt);
    k_irfft2b<<<4096, 256, 0, stream>>>(Sb, Hb);
    k_wprep<<<576, 256, 0, stream>>>(cwa, cwb, Wb);
    k_conv_mfma<<<dim3(32, 32), 256, 0, stream>>>(Hb, Wb, cba, cbb, Ub);
    k_helm<<<2048, 256, 0, stream>>>(Ub, H1b, partials);
    k_gnfin<<<1, 128, 0, stream>>>(partials, gs);
    k_gnapply<<<8192, 256, 0, stream>>>(H1b, gs, gnw, gnb, out);
}

// Round 7
// 264.908 us; speedup vs baseline: 1.1718x; 1.1718x over previous
//
#include <hip/hip_runtime.h>
#include <math.h>

#define PI_F 3.14159265358979323846f

// Original strides (3 blocks/CU at 53248 B LDS) + XOR slot swizzle for conflicts.
#define RST 65   // real (float) row stride
#define CS  66   // complex stage stride (float2)
#define KS  34   // ky-layout stride (float2)
#define NBUF 2178

typedef __attribute__((ext_vector_type(8))) short short8;
typedef __attribute__((ext_vector_type(4))) float f32x4;
typedef __attribute__((ext_vector_type(4))) unsigned short u16x4;
typedef __attribute__((ext_vector_type(8))) unsigned short u16x8;

// stage-layout address: row*CS + intra, with intra's low 3 bits XOR'd by row&7.
// g(row)=2*row+(b^row) is injective mod 16 -> 4 lanes per float2-slot residue
// on every transposed read pattern (was 8 = parity-locked).
static __device__ __forceinline__ int sw(int row, int intra) {
    return row * CS + (intra ^ (row & 7));
}

static __device__ __forceinline__ unsigned short f2bf(float x) {
    unsigned u = __float_as_uint(x);
    unsigned r = (u + 0x7FFF + ((u >> 16) & 1)) >> 16;
    return (unsigned short)r;
}
static __device__ __forceinline__ float bf2f(unsigned short u) {
    return __uint_as_float(((unsigned)u) << 16);
}

static __device__ __forceinline__ float2 cadd(float2 a, float2 b) { return make_float2(a.x + b.x, a.y + b.y); }
static __device__ __forceinline__ float2 csub(float2 a, float2 b) { return make_float2(a.x - b.x, a.y - b.y); }
static __device__ __forceinline__ float2 cmul(float2 a, float2 b) { return make_float2(a.x * b.x - a.y * b.y, a.x * b.y + a.y * b.x); }
static __device__ __forceinline__ float2 cmulc(float2 a, float2 b) { return make_float2(a.x * b.x + a.y * b.y, a.y * b.x - a.x * b.y); }

template <int S>
static __device__ __forceinline__ void dft8(float2* z) {
    const float RT = 0.70710678118654752440f;
    float2 ee0 = cadd(z[0], z[4]), ee1 = csub(z[0], z[4]);
    float2 eo0 = cadd(z[2], z[6]), eo1 = csub(z[2], z[6]);
    float2 oe0 = cadd(z[1], z[5]), oe1 = csub(z[1], z[5]);
    float2 oo0 = cadd(z[3], z[7]), oo1 = csub(z[3], z[7]);
    float2 ieo1 = make_float2(-S * eo1.y, S * eo1.x);
    float2 ioo1 = make_float2(-S * oo1.y, S * oo1.x);
    float2 E0 = cadd(ee0, eo0), E2 = csub(ee0, eo0);
    float2 E1 = cadd(ee1, ieo1), E3 = csub(ee1, ieo1);
    float2 O0 = cadd(oe0, oo0), O2 = csub(oe0, oo0);
    float2 O1 = cadd(oe1, ioo1), O3 = csub(oe1, ioo1);
    float2 w1O1 = make_float2(RT * (O1.x - S * O1.y), RT * (S * O1.x + O1.y));
    float2 w3O3 = make_float2(RT * (-O3.x - S * O3.y), RT * (S * O3.x - O3.y));
    float2 iO2  = make_float2(-S * O2.y, S * O2.x);
    z[0] = cadd(E0, O0);   z[4] = csub(E0, O0);
    z[1] = cadd(E1, w1O1); z[5] = csub(E1, w1O1);
    z[2] = cadd(E2, iO2);  z[6] = csub(E2, iO2);
    z[3] = cadd(E3, w3O3); z[7] = csub(E3, w3O3);
}

// ---------------------------------------------------------------- k_params
__global__ __launch_bounds__(256) void k_params(const float* __restrict__ stats,
                                                const float* __restrict__ gw,
                                                const float* __restrict__ gb,
                                                const float* __restrict__ dts,
                                                float2* __restrict__ A,
                                                float2* __restrict__ Xt) {
    int idx = blockIdx.x * 256 + threadIdx.x;
    int c = idx & 127;
    int bt = idx >> 7;
    const float* st = stats + bt * 128;
    float nu = gb[c], om = gb[c + 128];
    for (int k = 0; k < 128; ++k) {
        float s = st[k];
        nu += s * gw[k * 256 + c];
        om += s * gw[k * 256 + c + 128];
    }
    float dt = dts[bt];
    float lre = -fabsf(nu);
    float lim = om;
    float mag = sqrtf(lre * lre + lim * lim);
    float er = expf(lre * dt);
    float sn, cs;
    sincosf(lim * dt, &sn, &cs);
    float2 Av = make_float2(er * cs, er * sn);
    float2 X;
    if (mag < 1e-6f) {
        X = make_float2(dt, 0.f);
    } else {
        float ar = Av.x - 1.f, ai = Av.y;
        float inv = 1.f / (mag * mag);
        X = make_float2((ar * lre + ai * lim) * inv, (ai * lre - ar * lim) * inv);
    }
    A[idx] = Av;
    Xt[idx] = X;
}

// ---------------------------------------------------------------- k_rfft2s (radix-8, fused stats, bf16 spectra out)
__global__ __launch_bounds__(256) void k_rfft2s(const float* __restrict__ xin,
                                                unsigned* __restrict__ Sb,
                                                float* __restrict__ stats) {
    int img = blockIdx.x, tid = threadIdx.x;
    __shared__ float2 bufA[NBUF], bufB[NBUF], bufC[NBUF], twl[64];
    __shared__ float red[4];
    float* Af = (float*)bufA;
    if (tid < 64) {
        float sn, cs;
        sincosf(-(2.0f * PI_F / 64.0f) * (float)tid, &sn, &cs);
        twl[tid] = make_float2(cs, sn);
    }
    const float* xp = xin + (size_t)img * 4096;
    float ssum = 0.f;
    for (int i4 = tid; i4 < 1024; i4 += 256) {
        float4 v = ((const float4*)xp)[i4];
        ssum += v.x + v.y + v.z + v.w;
        int r = i4 >> 4, w = (i4 & 15) << 2;
        float* d = Af + r * RST + w;
        d[0] = v.x; d[1] = v.y; d[2] = v.z; d[3] = v.w;
    }
    for (int off = 32; off > 0; off >>= 1) ssum += __shfl_xor(ssum, off, 64);
    if ((tid & 63) == 0) red[tid >> 6] = ssum;
    __syncthreads();
    if (tid == 0) stats[img] = (red[0] + red[1] + red[2] + red[3]) * (1.0f / 4096.0f);

    // P2: row FFT stage A (rows packed in pairs).
    {
        int j = tid >> 3, b = tid & 7;
        const float* p0 = Af + (2 * j) * RST + b;
        const float* p1 = p0 + RST;
        float2 z[8];
#pragma unroll
        for (int a = 0; a < 8; ++a) z[a] = make_float2(p0[8 * a], p1[8 * a]);
        dft8<-1>(z);
#pragma unroll
        for (int c = 0; c < 8; ++c) bufB[sw(j, c * 8 + b)] = cmul(z[c], twl[(b * c) & 63]);
    }
    __syncthreads();

    // P3: row FFT stage B.
    {
        int j = tid >> 3, c = tid & 7;
        float2 z[8];
#pragma unroll
        for (int b = 0; b < 8; ++b) z[b] = bufB[sw(j, c * 8 + b)];
        dft8<-1>(z);
#pragma unroll
        for (int d = 0; d < 8; ++d) bufC[sw(j, c + 8 * d)] = z[d];
    }
    __syncthreads();

    // P4: Hermitian unpack -> transposed.
    for (int idx = tid; idx < 1056; idx += 256) {
        int j = idx / 33, k = idx - j * 33;
        float2 zk = bufC[sw(j, k)];
        float2 zm = bufC[sw(j, (64 - k) & 63)];
        bufA[sw(k, 2 * j)]     = make_float2((zk.x + zm.x) * 0.5f, (zk.y - zm.y) * 0.5f);
        bufA[sw(k, 2 * j + 1)] = make_float2((zk.y + zm.y) * 0.5f, (zm.x - zk.x) * 0.5f);
    }
    __syncthreads();

    // P5: column FFT stage A.
    auto colA = [&](int kx, int b) {
        float2 z[8];
#pragma unroll
        for (int a = 0; a < 8; ++a) z[a] = bufA[sw(kx, 8 * a + b)];
        dft8<-1>(z);
#pragma unroll
        for (int c = 0; c < 8; ++c) bufB[sw(kx, c * 8 + b)] = cmul(z[c], twl[(b * c) & 63]);
    };
    colA(tid >> 3, tid & 7);
    if (tid < 8) colA(32, tid);
    __syncthreads();

    // P6: column FFT stage B -> C[ky*KS+kx].
    auto colB = [&](int kx, int c) {
        float2 z[8];
#pragma unroll
        for (int b = 0; b < 8; ++b) z[b] = bufB[sw(kx, c * 8 + b)];
        dft8<-1>(z);
#pragma unroll
        for (int d = 0; d < 8; ++d) bufC[(c + 8 * d) * KS + kx] = z[d];
    };
    colB(tid >> 3, tid & 7);
    if (tid < 8) colB(32, tid);
    __syncthreads();

    // P7: ortho scale, bf16 pack, coalesced store.
    unsigned* op = Sb + (size_t)img * 2112;
    for (int i = tid; i < 2112; i += 256) {
        int ky = i / 33, kx = i - ky * 33;
        float2 v = bufC[ky * KS + kx];
        unsigned lo = f2bf(v.x * (1.0f / 64.0f));
        unsigned hi = f2bf(v.y * (1.0f / 64.0f));
        op[i] = lo | (hi << 16);
    }
}

// ---------------------------------------------------------------- k_scan (bf16 spectra, fused Xterm)
__global__ __launch_bounds__(256) void k_scan(unsigned* __restrict__ Sb,
                                              const float2* __restrict__ A,
                                              const float2* __restrict__ Xt) {
    int tid = blockIdx.x * 256 + threadIdx.x;
    int spec = tid % 2112;
    int c = (tid / 2112) & 127;
    int b = tid / (2112 * 128);
    float2 h = make_float2(0.f, 0.f);
    for (int t = 0; t < 16; ++t) {
        int bt = b * 16 + t;
        float2 a = A[bt * 128 + c];
        float2 xt = Xt[bt * 128 + c];
        size_t off = ((size_t)(bt * 128 + c)) * 2112 + spec;
        unsigned v = Sb[off];
        float2 xr = make_float2(bf2f((unsigned short)(v & 0xffff)), bf2f((unsigned short)(v >> 16)));
        float2 x = cmul(xr, xt);
        float hr = a.x * h.x - a.y * h.y + x.x;
        float hi = a.x * h.y + a.y * h.x + x.y;
        h = make_float2(hr, hi);
        Sb[off] = (unsigned)f2bf(hr) | ((unsigned)f2bf(hi) << 16);
    }
}

// ---------------------------------------------------------------- k_irfft2b (radix-8, bf16 in/out)
__global__ __launch_bounds__(256) void k_irfft2b(const unsigned* __restrict__ Sb,
                                                 unsigned short* __restrict__ hb) {
    int img = blockIdx.x, tid = threadIdx.x;
    __shared__ float2 bufA[NBUF], bufB[NBUF], bufC[NBUF], twl[64];
    float* Cf = (float*)bufC;
    if (tid < 64) {
        float sn, cs;
        sincosf(-(2.0f * PI_F / 64.0f) * (float)tid, &sn, &cs);
        twl[tid] = make_float2(cs, sn);
    }
    const unsigned* ip = Sb + (size_t)img * 2112;
    for (int i = tid; i < 2112; i += 256) {
        int ky = i / 33, kx = i - ky * 33;
        unsigned v = ip[i];
        bufA[ky * KS + kx] = make_float2(bf2f((unsigned short)(v & 0xffff)), bf2f((unsigned short)(v >> 16)));
    }
    __syncthreads();

    auto colA = [&](int kx, int b) {
        float2 z[8];
#pragma unroll
        for (int a = 0; a < 8; ++a) z[a] = bufA[(8 * a + b) * KS + kx];
        dft8<1>(z);
#pragma unroll
        for (int c = 0; c < 8; ++c) bufB[sw(kx, c * 8 + b)] = cmulc(z[c], twl[(b * c) & 63]);
    };
    colA(tid >> 3, tid & 7);
    if (tid < 8) colA(32, tid);
    __syncthreads();

    auto colB = [&](int kx, int c) {
        float2 z[8];
#pragma unroll
        for (int b = 0; b < 8; ++b) z[b] = bufB[sw(kx, c * 8 + b)];
        dft8<1>(z);
#pragma unroll
        for (int d = 0; d < 8; ++d) bufC[(c + 8 * d) * KS + kx] = z[d];
    };
    colB(tid >> 3, tid & 7);
    if (tid < 8) colB(32, tid);
    __syncthreads();

    // pack row pairs; irfft semantics: drop imag of DC/Nyquist kx bins.
    for (int idx = tid; idx < 2048; idx += 256) {
        int j = idx >> 6, k = idx & 63;
        int kk = (k <= 32) ? k : 64 - k;
        float2 t0 = bufC[(2 * j) * KS + kk];
        float2 t1 = bufC[(2 * j + 1) * KS + kk];
        if (kk == 0 || kk == 32) { t0.y = 0.f; t1.y = 0.f; }
        float sgn = (k <= 32) ? 1.f : -1.f;
        t0.y *= sgn; t1.y *= sgn;
        bufA[sw(j, k)] = make_float2(t0.x - t1.y, t0.y + t1.x);
    }
    __syncthreads();

    {
        int j = tid >> 3, b = tid & 7;
        float2 z[8];
#pragma unroll
        for (int a = 0; a < 8; ++a) z[a] = bufA[sw(j, 8 * a + b)];
        dft8<1>(z);
#pragma unroll
        for (int c = 0; c < 8; ++c) bufB[sw(j, c * 8 + b)] = cmulc(z[c], twl[(b * c) & 63]);
    }
    __syncthreads();

    {
        int j = tid >> 3, c = tid & 7;
        float2 z[8];
#pragma unroll
        for (int b = 0; b < 8; ++b) z[b] = bufB[sw(j, c * 8 + b)];
        dft8<1>(z);
#pragma unroll
        for (int d = 0; d < 8; ++d) {
            int w = c + 8 * d;
            Cf[(2 * j) * RST + w]     = z[d].x;
            Cf[(2 * j + 1) * RST + w] = z[d].y;
        }
    }
    __syncthreads();

    unsigned short* op = hb + (size_t)img * 4096;
    for (int i4 = tid; i4 < 1024; i4 += 256) {
        int r = i4 >> 4, w = (i4 & 15) << 2;
        const float* s = Cf + r * RST + w;
        u16x4 o;
        o[0] = f2bf(s[0] * (1.0f / 64.0f));
        o[1] = f2bf(s[1] * (1.0f / 64.0f));
        o[2] = f2bf(s[2] * (1.0f / 64.0f));
        o[3] = f2bf(s[3] * (1.0f / 64.0f));
        ((u16x4*)op)[i4] = o;
    }
}

// ---------------------------------------------------------------- k_wprep
__global__ __launch_bounds__(256) void k_wprep(const float* __restrict__ cwa,
                                               const float* __restrict__ cwb,
                                               unsigned short* __restrict__ Wb) {
    int idx = blockIdx.x * 256 + threadIdx.x;   // 147456 total
    int kl = idx & 31;
    int m = (idx >> 5) & 127;
    int tcb = idx >> 12;          // 0..35
    int cb = tcb & 3, t = tcb >> 2;
    int ci = cb * 32 + kl;
    int mm = m & 63, cc = ci & 63;
    float w;
    if (m < 64) w = (ci < 64) ? cwa[(mm * 64 + cc) * 9 + t] : -cwb[(mm * 64 + cc) * 9 + t];
    else        w = (ci < 64) ? cwb[(mm * 64 + cc) * 9 + t] :  cwa[(mm * 64 + cc) * 9 + t];
    if (m == ci && t == 4) w += 1.0f;   // residual folded into center tap
    Wb[idx] = f2bf(w);
}

// ---------------------------------------------------------------- k_conv_mfma (bf16 in, bf16 out)
__global__ __launch_bounds__(256, 2) void k_conv_mfma(const unsigned short* __restrict__ hb,
                                                      const unsigned short* __restrict__ Wb,
                                                      const float* __restrict__ cba,
                                                      const float* __restrict__ cbb,
                                                      unsigned short* __restrict__ uout) {
    __shared__ __align__(16) char smem[65536];
    int f = blockIdx.y;
    int r0 = blockIdx.x * 2;
    int tid = threadIdx.x;
    const unsigned short* base = hb + (size_t)f * 524288;

    for (int j = tid; j < 4096; j += 256) {
        int row = j >> 10;
        int cig = (j >> 6) & 15;
        int col = j & 63;
        int gr = r0 - 1 + row;
        short8 v = (short8)0;
        if ((unsigned)gr < 64u) {
            const unsigned short* p = base + (size_t)(cig * 8) * 4096 + gr * 64 + col;
#pragma unroll
            for (int e = 0; e < 8; ++e) v[e] = (short)p[(size_t)e * 4096];
        }
        int byteoff = ((row * 64 + col) << 8) + ((cig ^ (col & 15)) << 4);
        *(short8*)(smem + byteoff) = v;
    }
    __syncthreads();

    int wid = tid >> 6, lane = tid & 63;
    int lhi = lane >> 4, llo = lane & 15;
    int row_off = wid & 1;
    int mbase = (wid >> 1) * 64;

    f32x4 acc[4][4];
#pragma unroll
    for (int mf = 0; mf < 4; ++mf)
#pragma unroll
        for (int nf = 0; nf < 4; ++nf) acc[mf][nf] = (f32x4)0.f;

    for (int t = 0; t < 9; ++t) {
        int dy = t / 3 - 1, dx = t % 3 - 1;
        int prow = row_off + 1 + dy;
#pragma unroll
        for (int cb = 0; cb < 4; ++cb) {
            short8 a[4];
            const unsigned short* wp = Wb + ((size_t)((t * 4 + cb) * 128 + mbase + llo)) * 32 + lhi * 8;
#pragma unroll
            for (int mf = 0; mf < 4; ++mf) a[mf] = *(const short8*)(wp + mf * 16 * 32);
            short8 b[4];
            int slot = cb * 4 + lhi;
#pragma unroll
            for (int nf = 0; nf < 4; ++nf) {
                int c = nf * 16 + llo;
                int cdx = c + dx;
                bool valid = ((unsigned)cdx < 64u);
                int cr = valid ? cdx : c;
                int byteoff = ((prow * 64 + cr) << 8) + ((slot ^ (cr & 15)) << 4);
                short8 bb = *(const short8*)(smem + byteoff);
                b[nf] = valid ? bb : (short8)0;
            }
#pragma unroll
            for (int mf = 0; mf < 4; ++mf)
#pragma unroll
                for (int nf = 0; nf < 4; ++nf)
                    acc[mf][nf] = __builtin_amdgcn_mfma_f32_16x16x32_bf16(a[mf], b[nf], acc[mf][nf], 0, 0, 0);
        }
    }

    int grow = r0 + row_off;
#pragma unroll
    for (int mf = 0; mf < 4; ++mf) {
#pragma unroll
        for (int r = 0; r < 4; ++r) {
            int co = mbase + mf * 16 + lhi * 4 + r;
            float bias = (co < 64) ? cba[co] : cbb[co - 64];
            unsigned short* op = uout + ((size_t)f * 128 + co) * 4096 + (size_t)grow * 64;
#pragma unroll
            for (int nf = 0; nf < 4; ++nf)
                op[nf * 16 + llo] = f2bf(acc[mf][nf][r] + bias);
        }
    }
}

// ---------------------------------------------------------------- k_helm (fused rfft2 + project + irfft2 + GN partials)
// Block = (frame f, channel c in 0..63). Handles images (f, c) and (f, c+64). bf16 in/out.
__global__ __launch_bounds__(256) void k_helm(const unsigned short* __restrict__ uin,
                                              unsigned short* __restrict__ uo,
                                              float* __restrict__ partials) {
    int bid = blockIdx.x;
    int f = bid >> 6, c = bid & 63;
    int tid = threadIdx.x;
    __shared__ float2 W0[NBUF], W1[NBUF], SP[NBUF], twl[64];
    __shared__ float red[4];
    if (tid < 64) {
        float sn, cs;
        sincosf(-(2.0f * PI_F / 64.0f) * (float)tid, &sn, &cs);
        twl[tid] = make_float2(cs, sn);
    }

    auto loadimg = [&](const unsigned short* xp, float2* W) {
        float* Wf = (float*)W;
        for (int i4 = tid; i4 < 1024; i4 += 256) {
            u16x4 v = ((const u16x4*)xp)[i4];
            int r = i4 >> 4, w = (i4 & 15) << 2;
            float* d = Wf + r * RST + w;
            d[0] = bf2f(v[0]); d[1] = bf2f(v[1]); d[2] = bf2f(v[2]); d[3] = bf2f(v[3]);
        }
    };
    auto fwdP2 = [&](const float2* src, float2* dst) {
        const float* Af = (const float*)src;
        int j = tid >> 3, b = tid & 7;
        const float* p0 = Af + (2 * j) * RST + b;
        const float* p1 = p0 + RST;
        float2 z[8];
#pragma unroll
        for (int a = 0; a < 8; ++a) z[a] = make_float2(p0[8 * a], p1[8 * a]);
        dft8<-1>(z);
#pragma unroll
        for (int cc = 0; cc < 8; ++cc) dst[sw(j, cc * 8 + b)] = cmul(z[cc], twl[(b * cc) & 63]);
    };
    auto fwdP3 = [&](const float2* src, float2* dst) {
        int j = tid >> 3, cc = tid & 7;
        float2 z[8];
#pragma unroll
        for (int b = 0; b < 8; ++b) z[b] = src[sw(j, cc * 8 + b)];
        dft8<-1>(z);
#pragma unroll
        for (int d = 0; d < 8; ++d) dst[sw(j, cc + 8 * d)] = z[d];
    };
    auto fwdP4 = [&](const float2* src, float2* dst) {
        for (int idx = tid; idx < 1056; idx += 256) {
            int j = idx / 33, k = idx - j * 33;
            float2 zk = src[sw(j, k)];
            float2 zm = src[sw(j, (64 - k) & 63)];
            dst[sw(k, 2 * j)]     = make_float2((zk.x + zm.x) * 0.5f, (zk.y - zm.y) * 0.5f);
            dst[sw(k, 2 * j + 1)] = make_float2((zk.y + zm.y) * 0.5f, (zm.x - zk.x) * 0.5f);
        }
    };
    auto fwdP5 = [&](const float2* src, float2* dst) {
        auto body = [&](int kx, int b) {
            float2 z[8];
#pragma unroll
            for (int a = 0; a < 8; ++a) z[a] = src[sw(kx, 8 * a + b)];
            dft8<-1>(z);
#pragma unroll
            for (int cc = 0; cc < 8; ++cc) dst[sw(kx, cc * 8 + b)] = cmul(z[cc], twl[(b * cc) & 63]);
        };
        body(tid >> 3, tid & 7);
        if (tid < 8) body(32, tid);
    };
    auto fwdP6 = [&](const float2* src, float2* dst) {
        auto body = [&](int kx, int cc) {
            float2 z[8];
#pragma unroll
            for (int b = 0; b < 8; ++b) z[b] = src[sw(kx, cc * 8 + b)];
            dft8<-1>(z);
#pragma unroll
            for (int d = 0; d < 8; ++d) dst[(cc + 8 * d) * KS + kx] = z[d];
        };
        body(tid >> 3, tid & 7);
        if (tid < 8) body(32, tid);
    };
    auto invA = [&](const float2* src, float2* dst) {
        auto body = [&](int kx, int b) {
            float2 z[8];
#pragma unroll
            for (int a = 0; a < 8; ++a) z[a] = src[(8 * a + b) * KS + kx];
            dft8<1>(z);
#pragma unroll
            for (int cc = 0; cc < 8; ++cc) dst[sw(kx, cc * 8 + b)] = cmulc(z[cc], twl[(b * cc) & 63]);
        };
        body(tid >> 3, tid & 7);
        if (tid < 8) body(32, tid);
    };
    auto invB = [&](const float2* src, float2* dst) {
        auto body = [&](int kx, int cc) {
            float2 z[8];
#pragma unroll
            for (int b = 0; b < 8; ++b) z[b] = src[sw(kx, cc * 8 + b)];
            dft8<1>(z);
#pragma unroll
            for (int d = 0; d < 8; ++d) dst[(cc + 8 * d) * KS + kx] = z[d];
        };
        body(tid >> 3, tid & 7);
        if (tid < 8) body(32, tid);
    };
    auto invP4 = [&](const float2* src, float2* dst) {
        for (int idx = tid; idx < 2048; idx += 256) {
            int j = idx >> 6, k = idx & 63;
            int kk = (k <= 32) ? k : 64 - k;
            float2 t0 = src[(2 * j) * KS + kk];
            float2 t1 = src[(2 * j + 1) * KS + kk];
            if (kk == 0 || kk == 32) { t0.y = 0.f; t1.y = 0.f; }
            float sgn = (k <= 32) ? 1.f : -1.f;
            t0.y *= sgn; t1.y *= sgn;
            dst[sw(j, k)] = make_float2(t0.x - t1.y, t0.y + t1.x);
        }
    };
    auto invP5 = [&](const float2* src, float2* dst) {
        int j = tid >> 3, b = tid & 7;
        float2 z[8];
#pragma unroll
        for (int a = 0; a < 8; ++a) z[a] = src[sw(j, 8 * a + b)];
        dft8<1>(z);
#pragma unroll
        for (int cc = 0; cc < 8; ++cc) dst[sw(j, cc * 8 + b)] = cmulc(z[cc], twl[(b * cc) & 63]);
    };
    auto invP6 = [&](const float2* src, float2* dst) {
        float* Df = (float*)dst;
        int j = tid >> 3, cc = tid & 7;
        float2 z[8];
#pragma unroll
        for (int b = 0; b < 8; ++b) z[b] = src[sw(j, cc * 8 + b)];
        dft8<1>(z);
#pragma unroll
        for (int d = 0; d < 8; ++d) {
            int w = cc + 8 * d;
            Df[(2 * j) * RST + w]     = z[d].x;
            Df[(2 * j + 1) * RST + w] = z[d].y;
        }
    };
    auto writeimg = [&](const float2* W, unsigned short* op, int pslot) {
        const float* Wf = (const float*)W;
        float s = 0.f, q = 0.f;
        for (int i4 = tid; i4 < 1024; i4 += 256) {
            int r = i4 >> 4, w = (i4 & 15) << 2;
            const float* sp = Wf + r * RST + w;
            float a0 = sp[0] * (1.0f / 4096.0f), a1 = sp[1] * (1.0f / 4096.0f);
            float a2 = sp[2] * (1.0f / 4096.0f), a3 = sp[3] * (1.0f / 4096.0f);
            s += a0 + a1 + a2 + a3;
            q += a0 * a0 + a1 * a1 + a2 * a2 + a3 * a3;
            u16x4 o; o[0] = f2bf(a0); o[1] = f2bf(a1); o[2] = f2bf(a2); o[3] = f2bf(a3);
            ((u16x4*)op)[i4] = o;
        }
        for (int off = 32; off > 0; off >>= 1) {
            s += __shfl_xor(s, off, 64);
            q += __shfl_xor(q, off, 64);
        }
        __syncthreads();
        if ((tid & 63) == 0) { red[tid >> 6] = s; }
        __syncthreads();
        float stot = (tid == 0) ? (red[0] + red[1] + red[2] + red[3]) : 0.f;
        __syncthreads();
        if ((tid & 63) == 0) { red[tid >> 6] = q; }
        __syncthreads();
        if (tid == 0) {
            float qtot = red[0] + red[1] + red[2] + red[3];
            float* pp = partials + ((size_t)f * 64 + c) * 4 + pslot * 2;
            pp[0] = stot;
            pp[1] = qtot;
        }
    };

    const unsigned short* u0 = uin + ((size_t)f * 128 + c) * 4096;
    const unsigned short* u1 = uin + ((size_t)f * 128 + 64 + c) * 4096;
    unsigned short* o0 = uo + ((size_t)f * 128 + c) * 4096;
    unsigned short* o1 = uo + ((size_t)f * 128 + 64 + c) * 4096;

    // forward image0 -> SP
    loadimg(u0, W0);            __syncthreads();
    fwdP2(W0, W1);              __syncthreads();
    fwdP3(W1, W0);              __syncthreads();
    fwdP4(W0, W1);              __syncthreads();
    fwdP5(W1, W0);              __syncthreads();
    fwdP6(W0, SP);              __syncthreads();
    // forward image1 -> W1
    loadimg(u1, W0);            __syncthreads();
    fwdP2(W0, W1);              __syncthreads();
    fwdP3(W1, W0);              __syncthreads();
    fwdP4(W0, W1);              __syncthreads();
    fwdP5(W1, W0);              __syncthreads();
    fwdP6(W0, W1);              __syncthreads();

    // Helmholtz projection: SP = vx spectrum, W1 = vy spectrum (KS-layout).
    for (int i = tid; i < 64 * KS; i += 256) {
        int ky = i / KS, kx = i - ky * KS;
        if (kx > 32) continue;
        float kxv = (float)kx * (1.0f / 64.0f);
        float kyv = (float)(ky < 32 ? ky : ky - 64) * (1.0f / 64.0f);
        float k2 = kxv * kxv + kyv * kyv;
        if (k2 > 0.f) {
            float2 vx = SP[i], vy = W1[i];
            float inv = 1.0f / k2;
            float pr = (kxv * vx.x + kyv * vy.x) * inv;
            float pi = (kxv * vx.y + kyv * vy.y) * inv;
            SP[i] = make_float2(vx.x - kxv * pr, vx.y - kxv * pi);
            W1[i] = make_float2(vy.x - kyv * pr, vy.y - kyv * pi);
        }
    }
    __syncthreads();

    // inverse image0: SP -> real
    invA(SP, W0);               __syncthreads();
    invB(W0, SP);               __syncthreads();
    invP4(SP, W0);              __syncthreads();
    invP5(W0, SP);              __syncthreads();
    invP6(SP, W0);              __syncthreads();
    writeimg(W0, o0, 0);        __syncthreads();
    // inverse image1: W1 -> real
    invA(W1, W0);               __syncthreads();
    invB(W0, W1);               __syncthreads();
    invP4(W1, W0);              __syncthreads();
    invP5(W0, W1);              __syncthreads();
    invP6(W1, W0);              __syncthreads();
    writeimg(W0, o1, 1);
}

// ---------------------------------------------------------------- k_gnfin
__global__ __launch_bounds__(128) void k_gnfin(const float* __restrict__ partials,
                                               float2* __restrict__ gs) {
    int i = threadIdx.x;          // 0..127 = f*4 + g
    int f = i >> 2, g = i & 3;
    const float4* p4 = (const float4*)partials;
    float s = 0.f, q = 0.f;
    if (g < 2) {
        for (int cc = 0; cc < 32; ++cc) {
            float4 p = p4[f * 64 + g * 32 + cc];
            s += p.x; q += p.y;
        }
    } else {
        for (int cc = 0; cc < 32; ++cc) {
            float4 p = p4[f * 64 + (g - 2) * 32 + cc];
            s += p.z; q += p.w;
        }
    }
    float mu = s * (1.0f / 131072.0f);
    float var = q * (1.0f / 131072.0f) - mu * mu;
    gs[i] = make_float2(mu, rsqrtf(var + 1e-5f));
}

// ---------------------------------------------------------------- k_gnapply (bf16 in, fp32 out)
__global__ __launch_bounds__(256) void k_gnapply(const unsigned short* __restrict__ u,
                                                 const float2* __restrict__ gs,
                                                 const float* __restrict__ gnw,
                                                 const float* __restrict__ gnb,
                                                 float* __restrict__ out) {
    size_t i8 = (size_t)blockIdx.x * 256 + threadIdx.x;   // 2,097,152 exact
    u16x8 v = ((const u16x8*)u)[i8];
    int cl = (int)(i8 >> 9);      // f*128 + c
    int c = cl & 127;
    int fg = cl >> 5;             // f*4 + g
    float2 ms = gs[fg];
    float sc = ms.y * gnw[c];
    float sh = gnb[c] - ms.x * sc;
    float4 r0, r1;
    r0.x = bf2f(v[0]) * sc + sh; r0.y = bf2f(v[1]) * sc + sh;
    r0.z = bf2f(v[2]) * sc + sh; r0.w = bf2f(v[3]) * sc + sh;
    r1.x = bf2f(v[4]) * sc + sh; r1.y = bf2f(v[5]) * sc + sh;
    r1.z = bf2f(v[6]) * sc + sh; r1.w = bf2f(v[7]) * sc + sh;
    ((float4*)out)[i8 * 2]     = r0;
    ((float4*)out)[i8 * 2 + 1] = r1;
}

// ---------------------------------------------------------------- launch
extern "C" void kernel_launch(void* const* d_in, const int* in_sizes, int n_in,
                              void* d_out, int out_size, void* d_ws, size_t ws_size,
                              hipStream_t stream) {
    (void)in_sizes; (void)n_in; (void)out_size; (void)ws_size;
    const float* x   = (const float*)d_in[0];
    const float* dts = (const float*)d_in[1];
    const float* gw  = (const float*)d_in[2];
    const float* gb  = (const float*)d_in[3];
    const float* cwa = (const float*)d_in[4];
    const float* cwb = (const float*)d_in[5];
    const float* cba = (const float*)d_in[6];
    const float* cbb = (const float*)d_in[7];
    const float* gnw = (const float*)d_in[8];
    const float* gnb = (const float*)d_in[9];
    float* out = (float*)d_out;
    char* ws = (char*)d_ws;

    unsigned*       Sb  = (unsigned*)ws;                       // 34,603,008 B (bf16 spectra)
    unsigned short* Hb  = (unsigned short*)(ws + 34603008);    // 33,554,432 B (bf16 h)
    unsigned short* Ub  = (unsigned short*)(ws + 68157440);    // 33,554,432 B (bf16 u)
    unsigned short* H1b = (unsigned short*)(ws + 101711872);   // 33,554,432 B (bf16 helm out)
    float*  stats    = (float*)(ws + 135266304);               // 16,384 B
    float2* A        = (float2*)(ws + 135282688);              // 32,768 B
    float2* Xt       = (float2*)(ws + 135315456);              // 32,768 B
    float2* gs       = (float2*)(ws + 135348224);              // 1,024 B
    float*  partials = (float*)(ws + 135349248);               // 32,768 B
    unsigned short* Wb = (unsigned short*)ws;                  // aliases Sb (dead after irfft2b)

    k_rfft2s<<<4096, 256, 0, stream>>>(x, Sb, stats);
    k_params<<<16, 256, 0, stream>>>(stats, gw, gb, dts, A, Xt);
    k_scan<<<2112, 256, 0, stream>>>(Sb, A, Xt);
    k_irfft2b<<<4096, 256, 0, stream>>>(Sb, Hb);
    k_wprep<<<576, 256, 0, stream>>>(cwa, cwb, Wb);
    k_conv_mfma<<<dim3(32, 32), 256, 0, stream>>>(Hb, Wb, cba, cbb, Ub);
    k_helm<<<2048, 256, 0, stream>>>(Ub, H1b, partials);
    k_gnfin<<<1, 128, 0, stream>>>(partials, gs);
    k_gnapply<<<8192, 256, 0, stream>>>(H1b, gs, gnw, gnb, out);
}

// Round 8
// 222.166 us; speedup vs baseline: 1.3973x; 1.1924x over previous
//
#include <hip/hip_runtime.h>
#include <math.h>

#define PI_F 3.14159265358979323846f
#define ST 66   // float2 row stride of the 64x64 complex grid

typedef __attribute__((ext_vector_type(8))) short short8;
typedef __attribute__((ext_vector_type(4))) float f32x4;
typedef __attribute__((ext_vector_type(4))) unsigned short u16x4;
typedef __attribute__((ext_vector_type(8))) unsigned short u16x8;

// Element (row, intra) lives at row*ST + (intra ^ (row&7)). All grid accesses
// go through sw(); XOR key makes every FFT stage pattern ~conflict-free.
static __device__ __forceinline__ int sw(int row, int intra) {
    return row * ST + (intra ^ (row & 7));
}

static __device__ __forceinline__ unsigned short f2bf(float x) {
    unsigned u = __float_as_uint(x);
    unsigned r = (u + 0x7FFF + ((u >> 16) & 1)) >> 16;
    return (unsigned short)r;
}
static __device__ __forceinline__ float bf2f(unsigned short u) {
    return __uint_as_float(((unsigned)u) << 16);
}
static __device__ __forceinline__ float2 unpk(unsigned v) {
    return make_float2(bf2f((unsigned short)(v & 0xffff)), bf2f((unsigned short)(v >> 16)));
}

static __device__ __forceinline__ float2 cadd(float2 a, float2 b) { return make_float2(a.x + b.x, a.y + b.y); }
static __device__ __forceinline__ float2 csub(float2 a, float2 b) { return make_float2(a.x - b.x, a.y - b.y); }
static __device__ __forceinline__ float2 cmul(float2 a, float2 b) { return make_float2(a.x * b.x - a.y * b.y, a.x * b.y + a.y * b.x); }
static __device__ __forceinline__ float2 cmulc(float2 a, float2 b) { return make_float2(a.x * b.x + a.y * b.y, a.y * b.x - a.x * b.y); }

template <int S>
static __device__ __forceinline__ void dft8(float2* z) {
    const float RT = 0.70710678118654752440f;
    float2 ee0 = cadd(z[0], z[4]), ee1 = csub(z[0], z[4]);
    float2 eo0 = cadd(z[2], z[6]), eo1 = csub(z[2], z[6]);
    float2 oe0 = cadd(z[1], z[5]), oe1 = csub(z[1], z[5]);
    float2 oo0 = cadd(z[3], z[7]), oo1 = csub(z[3], z[7]);
    float2 ieo1 = make_float2(-S * eo1.y, S * eo1.x);
    float2 ioo1 = make_float2(-S * oo1.y, S * oo1.x);
    float2 E0 = cadd(ee0, eo0), E2 = csub(ee0, eo0);
    float2 E1 = cadd(ee1, ieo1), E3 = csub(ee1, ieo1);
    float2 O0 = cadd(oe0, oo0), O2 = csub(oe0, oo0);
    float2 O1 = cadd(oe1, ioo1), O3 = csub(oe1, ioo1);
    float2 w1O1 = make_float2(RT * (O1.x - S * O1.y), RT * (S * O1.x + O1.y));
    float2 w3O3 = make_float2(RT * (-O3.x - S * O3.y), RT * (S * O3.x - O3.y));
    float2 iO2  = make_float2(-S * O2.y, S * O2.x);
    z[0] = cadd(E0, O0);   z[4] = csub(E0, O0);
    z[1] = cadd(E1, w1O1); z[5] = csub(E1, w1O1);
    z[2] = cadd(E2, iO2);  z[6] = csub(E2, iO2);
    z[3] = cadd(E3, w3O3); z[7] = csub(E3, w3O3);
}

// ---- 64-pt FFT along intra axis (rows) and row axis (cols), in-place grid ----
template <int S>
static __device__ __forceinline__ void fftRowsA(float2* G, const float2* twl, int tid) {
#pragma unroll
    for (int sl = 0; sl < 2; ++sl) {
        int s = tid + sl * 256;
        int row = s >> 3, b = s & 7;
        float2 z[8];
#pragma unroll
        for (int a = 0; a < 8; ++a) z[a] = G[sw(row, 8 * a + b)];
        dft8<S>(z);
#pragma unroll
        for (int c = 0; c < 8; ++c) {
            float2 t = twl[(b * c) & 63];
            G[sw(row, 8 * c + b)] = (S < 0) ? cmul(z[c], t) : cmulc(z[c], t);
        }
    }
}
template <int S>
static __device__ __forceinline__ void fftRowsB(float2* G, int tid) {
    int r0 = tid >> 3, c = tid & 7, r1 = r0 + 32;
    float2 z0[8], z1[8];
#pragma unroll
    for (int b = 0; b < 8; ++b) z0[b] = G[sw(r0, 8 * c + b)];
#pragma unroll
    for (int b = 0; b < 8; ++b) z1[b] = G[sw(r1, 8 * c + b)];
    dft8<S>(z0); dft8<S>(z1);
    __syncthreads();
#pragma unroll
    for (int d = 0; d < 8; ++d) G[sw(r0, c + 8 * d)] = z0[d];
#pragma unroll
    for (int d = 0; d < 8; ++d) G[sw(r1, c + 8 * d)] = z1[d];
}
template <int S>
static __device__ __forceinline__ void fftColsA(float2* G, const float2* twl, int tid) {
#pragma unroll
    for (int sl = 0; sl < 2; ++sl) {
        int s = tid + sl * 256;
        int col = s & 63, b = s >> 6;
        float2 z[8];
#pragma unroll
        for (int a = 0; a < 8; ++a) z[a] = G[sw(8 * a + b, col)];
        dft8<S>(z);
#pragma unroll
        for (int c = 0; c < 8; ++c) {
            float2 t = twl[(b * c) & 63];
            G[sw(8 * c + b, col)] = (S < 0) ? cmul(z[c], t) : cmulc(z[c], t);
        }
    }
}
template <int S>
static __device__ __forceinline__ void fftColsB(float2* G, int tid) {
    int col = tid & 63, c0 = tid >> 6, c1 = c0 + 4;
    float2 z0[8], z1[8];
#pragma unroll
    for (int b = 0; b < 8; ++b) z0[b] = G[sw(8 * c0 + b, col)];
#pragma unroll
    for (int b = 0; b < 8; ++b) z1[b] = G[sw(8 * c1 + b, col)];
    dft8<S>(z0); dft8<S>(z1);
    __syncthreads();
#pragma unroll
    for (int d = 0; d < 8; ++d) G[sw(c0 + 8 * d, col)] = z0[d];
#pragma unroll
    for (int d = 0; d < 8; ++d) G[sw(c1 + 8 * d, col)] = z1[d];
}

// ---------------------------------------------------------------- k_params
__global__ __launch_bounds__(256) void k_params(const float* __restrict__ stats,
                                                const float* __restrict__ gw,
                                                const float* __restrict__ gb,
                                                const float* __restrict__ dts,
                                                float2* __restrict__ A,
                                                float2* __restrict__ Xt) {
    int idx = blockIdx.x * 256 + threadIdx.x;
    int c = idx & 127;
    int bt = idx >> 7;
    const float* st = stats + bt * 128;
    float nu = gb[c], om = gb[c + 128];
    for (int k = 0; k < 128; ++k) {
        float s = st[k];
        nu += s * gw[k * 256 + c];
        om += s * gw[k * 256 + c + 128];
    }
    float dt = dts[bt];
    float lre = -fabsf(nu);
    float lim = om;
    float mag = sqrtf(lre * lre + lim * lim);
    float er = expf(lre * dt);
    float sn, cs;
    sincosf(lim * dt, &sn, &cs);
    float2 Av = make_float2(er * cs, er * sn);
    float2 X;
    if (mag < 1e-6f) {
        X = make_float2(dt, 0.f);
    } else {
        float ar = Av.x - 1.f, ai = Av.y;
        float inv = 1.f / (mag * mag);
        X = make_float2((ar * lre + ai * lim) * inv, (ai * lre - ar * lim) * inv);
    }
    A[idx] = Av;
    Xt[idx] = X;
}

// ---------------------------------------------------------------- k_rfft2s
// Two images per block packed as z = x0 + i*x1; one complex 2D FFT; Hermitian
// split into two half-spectra (bf16). Fused per-image means.
__global__ __launch_bounds__(256) void k_rfft2s(const float* __restrict__ xin,
                                                unsigned* __restrict__ Sb,
                                                float* __restrict__ stats) {
    int p = blockIdx.x, tid = threadIdx.x;
    __shared__ float2 G[64 * ST], twl[64];
    __shared__ float red[8];
    if (tid < 64) {
        float sn, cs;
        sincosf(-(2.0f * PI_F / 64.0f) * (float)tid, &sn, &cs);
        twl[tid] = make_float2(cs, sn);
    }
    const float* x0 = xin + (size_t)(2 * p) * 4096;
    const float* x1 = x0 + 4096;
    float s0 = 0.f, s1 = 0.f;
    for (int i4 = tid; i4 < 1024; i4 += 256) {
        float4 a = ((const float4*)x0)[i4];
        float4 b = ((const float4*)x1)[i4];
        s0 += a.x + a.y + a.z + a.w;
        s1 += b.x + b.y + b.z + b.w;
        int r = i4 >> 4, w = (i4 & 15) << 2;
        G[sw(r, w + 0)] = make_float2(a.x, b.x);
        G[sw(r, w + 1)] = make_float2(a.y, b.y);
        G[sw(r, w + 2)] = make_float2(a.z, b.z);
        G[sw(r, w + 3)] = make_float2(a.w, b.w);
    }
    for (int off = 32; off > 0; off >>= 1) {
        s0 += __shfl_xor(s0, off, 64);
        s1 += __shfl_xor(s1, off, 64);
    }
    if ((tid & 63) == 0) { red[(tid >> 6) * 2] = s0; red[(tid >> 6) * 2 + 1] = s1; }
    __syncthreads();
    if (tid < 2) {
        float t = red[tid] + red[tid + 2] + red[tid + 4] + red[tid + 6];
        stats[2 * p + tid] = t * (1.0f / 4096.0f);
    }
    fftRowsA<-1>(G, twl, tid); __syncthreads();
    fftRowsB<-1>(G, tid);      __syncthreads();
    fftColsA<-1>(G, twl, tid); __syncthreads();
    fftColsB<-1>(G, tid);      __syncthreads();

    unsigned* o0 = Sb + (size_t)(2 * p) * 2112;
    unsigned* o1 = o0 + 2112;
    for (int i = tid; i < 2112; i += 256) {
        int my = i / 33, mx = i - my * 33;
        float2 Zk = G[sw(my, mx)];
        float2 Zm = G[sw((64 - my) & 63, (64 - mx) & 63)];
        float a0 = (Zk.x + Zm.x) * (0.5f / 64.0f);
        float a1 = (Zk.y - Zm.y) * (0.5f / 64.0f);
        float b0 = (Zk.y + Zm.y) * (0.5f / 64.0f);
        float b1 = (Zm.x - Zk.x) * (0.5f / 64.0f);
        o0[i] = (unsigned)f2bf(a0) | ((unsigned)f2bf(a1) << 16);
        o1[i] = (unsigned)f2bf(b0) | ((unsigned)f2bf(b1) << 16);
    }
}

// ---------------------------------------------------------------- k_scan
__global__ __launch_bounds__(256) void k_scan(unsigned* __restrict__ Sb,
                                              const float2* __restrict__ A,
                                              const float2* __restrict__ Xt) {
    int tid = blockIdx.x * 256 + threadIdx.x;
    int spec = tid % 2112;
    int c = (tid / 2112) & 127;
    int b = tid / (2112 * 128);
    float2 h = make_float2(0.f, 0.f);
    for (int t = 0; t < 16; ++t) {
        int bt = b * 16 + t;
        float2 a = A[bt * 128 + c];
        float2 xt = Xt[bt * 128 + c];
        size_t off = ((size_t)(bt * 128 + c)) * 2112 + spec;
        float2 xr = unpk(Sb[off]);
        float2 x = cmul(xr, xt);
        float hr = a.x * h.x - a.y * h.y + x.x;
        float hi = a.x * h.y + a.y * h.x + x.y;
        h = make_float2(hr, hi);
        Sb[off] = (unsigned)f2bf(hr) | ((unsigned)f2bf(hi) << 16);
    }
}

// ---------------------------------------------------------------- k_irfft2b
// Two spectra per block -> full complex grid (exact numpy-irfft semantics:
// Hermitian-x extension; y-Hermitianize kx in {0,32} = the imag-drop) ->
// one complex inverse FFT -> Re = img0, Im = img1 (bf16).
__global__ __launch_bounds__(256) void k_irfft2b(const unsigned* __restrict__ Sb,
                                                 unsigned short* __restrict__ hb) {
    int p = blockIdx.x, tid = threadIdx.x;
    __shared__ float2 G[64 * ST], twl[64];
    if (tid < 64) {
        float sn, cs;
        sincosf(-(2.0f * PI_F / 64.0f) * (float)tid, &sn, &cs);
        twl[tid] = make_float2(cs, sn);
    }
    const unsigned* i0 = Sb + (size_t)(2 * p) * 2112;
    const unsigned* i1 = i0 + 2112;
    for (int i = tid; i < 1984; i += 256) {
        int mx = 1 + i % 31, my = i / 31;
        int idx = my * 33 + mx;
        float2 a = unpk(i0[idx]);
        float2 b = unpk(i1[idx]);
        G[sw(my, mx)] = make_float2(a.x - b.y, a.y + b.x);
        G[sw((64 - my) & 63, 64 - mx)] = make_float2(a.x + b.y, b.x - a.y);
    }
    if (tid < 64) {
        int mx = (tid >= 32) ? 32 : 0;
        int r = tid & 31;
        if (r == 0) {
#pragma unroll
            for (int q = 0; q < 2; ++q) {
                int my = q * 32;
                float2 a = unpk(i0[my * 33 + mx]);
                float2 b = unpk(i1[my * 33 + mx]);
                G[sw(my, mx)] = make_float2(a.x, b.x);     // imag dropped
            }
        } else {
            int my = r, my2 = 64 - r;
            float2 A0 = unpk(i0[my * 33 + mx]),  B0 = unpk(i0[my2 * 33 + mx]);
            float2 A1 = unpk(i1[my * 33 + mx]),  B1 = unpk(i1[my2 * 33 + mx]);
            float2 V0 = make_float2((A0.x + B0.x) * 0.5f, (A0.y - B0.y) * 0.5f);
            float2 V1 = make_float2((A1.x + B1.x) * 0.5f, (A1.y - B1.y) * 0.5f);
            G[sw(my, mx)]  = make_float2(V0.x - V1.y, V0.y + V1.x);
            G[sw(my2, mx)] = make_float2(V0.x + V1.y, V1.x - V0.y);
        }
    }
    __syncthreads();
    fftColsA<1>(G, twl, tid); __syncthreads();
    fftColsB<1>(G, tid);      __syncthreads();
    fftRowsA<1>(G, twl, tid); __syncthreads();
    fftRowsB<1>(G, tid);      __syncthreads();

    unsigned short* h0 = hb + (size_t)(2 * p) * 4096;
    unsigned short* h1 = h0 + 4096;
    for (int i4 = tid; i4 < 1024; i4 += 256) {
        int r = i4 >> 4, w = (i4 & 15) << 2;
        u16x4 oa, ob;
#pragma unroll
        for (int e = 0; e < 4; ++e) {
            float2 v = G[sw(r, w + e)];
            oa[e] = f2bf(v.x * (1.0f / 64.0f));
            ob[e] = f2bf(v.y * (1.0f / 64.0f));
        }
        ((u16x4*)h0)[i4] = oa;
        ((u16x4*)h1)[i4] = ob;
    }
}

// ---------------------------------------------------------------- k_wprep
__global__ __launch_bounds__(256) void k_wprep(const float* __restrict__ cwa,
                                               const float* __restrict__ cwb,
                                               unsigned short* __restrict__ Wb) {
    int idx = blockIdx.x * 256 + threadIdx.x;
    int kl = idx & 31;
    int m = (idx >> 5) & 127;
    int tcb = idx >> 12;
    int cb = tcb & 3, t = tcb >> 2;
    int ci = cb * 32 + kl;
    int mm = m & 63, cc = ci & 63;
    float w;
    if (m < 64) w = (ci < 64) ? cwa[(mm * 64 + cc) * 9 + t] : -cwb[(mm * 64 + cc) * 9 + t];
    else        w = (ci < 64) ? cwb[(mm * 64 + cc) * 9 + t] :  cwa[(mm * 64 + cc) * 9 + t];
    if (m == ci && t == 4) w += 1.0f;
    Wb[idx] = f2bf(w);
}

// ---------------------------------------------------------------- k_conv_mfma
__global__ __launch_bounds__(256, 2) void k_conv_mfma(const unsigned short* __restrict__ hb,
                                                      const unsigned short* __restrict__ Wb,
                                                      const float* __restrict__ cba,
                                                      const float* __restrict__ cbb,
                                                      unsigned short* __restrict__ uout) {
    __shared__ __align__(16) char smem[65536];
    int f = blockIdx.y;
    int r0 = blockIdx.x * 2;
    int tid = threadIdx.x;
    const unsigned short* base = hb + (size_t)f * 524288;

    for (int j = tid; j < 4096; j += 256) {
        int row = j >> 10;
        int cig = (j >> 6) & 15;
        int col = j & 63;
        int gr = r0 - 1 + row;
        short8 v = (short8)0;
        if ((unsigned)gr < 64u) {
            const unsigned short* p = base + (size_t)(cig * 8) * 4096 + gr * 64 + col;
#pragma unroll
            for (int e = 0; e < 8; ++e) v[e] = (short)p[(size_t)e * 4096];
        }
        int byteoff = ((row * 64 + col) << 8) + ((cig ^ (col & 15)) << 4);
        *(short8*)(smem + byteoff) = v;
    }
    __syncthreads();

    int wid = tid >> 6, lane = tid & 63;
    int lhi = lane >> 4, llo = lane & 15;
    int row_off = wid & 1;
    int mbase = (wid >> 1) * 64;

    f32x4 acc[4][4];
#pragma unroll
    for (int mf = 0; mf < 4; ++mf)
#pragma unroll
        for (int nf = 0; nf < 4; ++nf) acc[mf][nf] = (f32x4)0.f;

    for (int t = 0; t < 9; ++t) {
        int dy = t / 3 - 1, dx = t % 3 - 1;
        int prow = row_off + 1 + dy;
#pragma unroll
        for (int cb = 0; cb < 4; ++cb) {
            short8 a[4];
            const unsigned short* wp = Wb + ((size_t)((t * 4 + cb) * 128 + mbase + llo)) * 32 + lhi * 8;
#pragma unroll
            for (int mf = 0; mf < 4; ++mf) a[mf] = *(const short8*)(wp + mf * 16 * 32);
            short8 b[4];
            int slot = cb * 4 + lhi;
#pragma unroll
            for (int nf = 0; nf < 4; ++nf) {
                int c = nf * 16 + llo;
                int cdx = c + dx;
                bool valid = ((unsigned)cdx < 64u);
                int cr = valid ? cdx : c;
                int byteoff = ((prow * 64 + cr) << 8) + ((slot ^ (cr & 15)) << 4);
                short8 bb = *(const short8*)(smem + byteoff);
                b[nf] = valid ? bb : (short8)0;
            }
#pragma unroll
            for (int mf = 0; mf < 4; ++mf)
#pragma unroll
                for (int nf = 0; nf < 4; ++nf)
                    acc[mf][nf] = __builtin_amdgcn_mfma_f32_16x16x32_bf16(a[mf], b[nf], acc[mf][nf], 0, 0, 0);
        }
    }

    int grow = r0 + row_off;
#pragma unroll
    for (int mf = 0; mf < 4; ++mf) {
#pragma unroll
        for (int r = 0; r < 4; ++r) {
            int co = mbase + mf * 16 + lhi * 4 + r;
            float bias = (co < 64) ? cba[co] : cbb[co - 64];
            unsigned short* op = uout + ((size_t)f * 128 + co) * 4096 + (size_t)grow * 64;
#pragma unroll
            for (int nf = 0; nf < 4; ++nf)
                op[nf * 16 + llo] = f2bf(acc[mf][nf][r] + bias);
        }
    }
}

// ---------------------------------------------------------------- k_helm
// Block = (frame f, channel c<64). z = vx + i*vy, complex FFT, Helmholtz
// projection with exact reference semantics, inverse FFT, Re/Im -> outputs,
// fused GN partials.
__global__ __launch_bounds__(256) void k_helm(const unsigned short* __restrict__ uin,
                                              unsigned short* __restrict__ uo,
                                              float* __restrict__ partials) {
    int bid = blockIdx.x;
    int f = bid >> 6, c = bid & 63;
    int tid = threadIdx.x;
    __shared__ float2 G[64 * ST], twl[64];
    __shared__ float red[16];
    if (tid < 64) {
        float sn, cs;
        sincosf(-(2.0f * PI_F / 64.0f) * (float)tid, &sn, &cs);
        twl[tid] = make_float2(cs, sn);
    }
    const unsigned short* u0 = uin + ((size_t)f * 128 + c) * 4096;
    const unsigned short* u1 = u0 + (size_t)64 * 4096;
    for (int i4 = tid; i4 < 1024; i4 += 256) {
        u16x4 a = ((const u16x4*)u0)[i4];
        u16x4 b = ((const u16x4*)u1)[i4];
        int r = i4 >> 4, w = (i4 & 15) << 2;
#pragma unroll
        for (int e = 0; e < 4; ++e)
            G[sw(r, w + e)] = make_float2(bf2f(a[e]), bf2f(b[e]));
    }
    __syncthreads();
    fftRowsA<-1>(G, twl, tid); __syncthreads();
    fftRowsB<-1>(G, tid);      __syncthreads();
    fftColsA<-1>(G, twl, tid); __syncthreads();
    fftColsB<-1>(G, tid);      __syncthreads();

    // projection: interior columns mx in [1,31]; ext bins = conj (Hermitian-x)
    for (int i = tid; i < 1984; i += 256) {
        int mx = 1 + i % 31, my = i / 31;
        float2 Zk = G[sw(my, mx)];
        float2 Zm = G[sw((64 - my) & 63, 64 - mx)];
        float2 Vx = make_float2((Zk.x + Zm.x) * 0.5f, (Zk.y - Zm.y) * 0.5f);
        float2 Vy = make_float2((Zk.y + Zm.y) * 0.5f, (Zm.x - Zk.x) * 0.5f);
        float fx = (float)mx * (1.0f / 64.0f);
        float fy = (float)(my < 32 ? my : my - 64) * (1.0f / 64.0f);
        float inv = 1.0f / (fx * fx + fy * fy);
        float Pr = (fx * Vx.x + fy * Vy.x) * inv;
        float Pi = (fx * Vx.y + fy * Vy.y) * inv;
        Vx.x -= fx * Pr; Vx.y -= fx * Pi;
        Vy.x -= fy * Pr; Vy.y -= fy * Pi;
        G[sw(my, mx)] = make_float2(Vx.x - Vy.y, Vx.y + Vy.x);
        G[sw((64 - my) & 63, 64 - mx)] = make_float2(Vx.x + Vy.y, Vy.x - Vx.y);
    }
    // columns mx in {0,32}: project both halves, then y-Hermitianize (imag-drop)
    if (tid < 64) {
        int mx = (tid >= 32) ? 32 : 0;
        int r = tid & 31;
        float fx = (float)mx * (1.0f / 64.0f);
        if (r == 0) {
#pragma unroll
            for (int q = 0; q < 2; ++q) {
                int my = q * 32;
                float fy = (my == 0) ? 0.f : -0.5f;
                float k2 = fx * fx + fy * fy;
                float2 Z = G[sw(my, mx)];
                float vx = Z.x, vy = Z.y;       // self bins: V real after drop
                if (k2 > 0.f) {
                    float P = (fx * vx + fy * vy) / k2;
                    vx -= fx * P; vy -= fy * P;
                }
                G[sw(my, mx)] = make_float2(vx, vy);
            }
        } else {
            int my = r, my2 = 64 - r;
            float fy = (float)my * (1.0f / 64.0f);
            float inv = 1.0f / (fx * fx + fy * fy);
            float2 Zk = G[sw(my, mx)];
            float2 Zm = G[sw(my2, mx)];
            float2 Vx = make_float2((Zk.x + Zm.x) * 0.5f, (Zk.y - Zm.y) * 0.5f);
            float2 Vy = make_float2((Zk.y + Zm.y) * 0.5f, (Zm.x - Zk.x) * 0.5f);
            float Pr = (fx * Vx.x + fy * Vy.x) * inv;
            float Pi = (fx * Vx.y + fy * Vy.y) * inv;
            float2 Xk = make_float2(Vx.x - fx * Pr, Vx.y - fx * Pi);
            float2 Yk = make_float2(Vy.x - fy * Pr, Vy.y - fy * Pi);
            float P2r = (fx * Vx.x - fy * Vy.x) * inv;    // at k2: V=conj(V), w=(fx,-fy)
            float P2i = (-fx * Vx.y + fy * Vy.y) * inv;
            float2 Xk2 = make_float2(Vx.x - fx * P2r, -Vx.y - fx * P2i);
            float2 Yk2 = make_float2(Vy.x + fy * P2r, -Vy.y + fy * P2i);
            float2 Xh = make_float2((Xk.x + Xk2.x) * 0.5f, (Xk.y - Xk2.y) * 0.5f);
            float2 Yh = make_float2((Yk.x + Yk2.x) * 0.5f, (Yk.y - Yk2.y) * 0.5f);
            G[sw(my, mx)]  = make_float2(Xh.x - Yh.y, Xh.y + Yh.x);
            G[sw(my2, mx)] = make_float2(Xh.x + Yh.y, Yh.x - Xh.y);
        }
    }
    __syncthreads();
    fftColsA<1>(G, twl, tid); __syncthreads();
    fftColsB<1>(G, tid);      __syncthreads();
    fftRowsA<1>(G, twl, tid); __syncthreads();
    fftRowsB<1>(G, tid);      __syncthreads();

    unsigned short* o0 = uo + ((size_t)f * 128 + c) * 4096;
    unsigned short* o1 = o0 + (size_t)64 * 4096;
    float s0 = 0.f, q0 = 0.f, s1 = 0.f, q1 = 0.f;
    for (int i4 = tid; i4 < 1024; i4 += 256) {
        int r = i4 >> 4, w = (i4 & 15) << 2;
        u16x4 oa, ob;
#pragma unroll
        for (int e = 0; e < 4; ++e) {
            float2 v = G[sw(r, w + e)];
            float a = v.x * (1.0f / 4096.0f);
            float b = v.y * (1.0f / 4096.0f);
            s0 += a; q0 += a * a; s1 += b; q1 += b * b;
            oa[e] = f2bf(a); ob[e] = f2bf(b);
        }
        ((u16x4*)o0)[i4] = oa;
        ((u16x4*)o1)[i4] = ob;
    }
    for (int off = 32; off > 0; off >>= 1) {
        s0 += __shfl_xor(s0, off, 64); q0 += __shfl_xor(q0, off, 64);
        s1 += __shfl_xor(s1, off, 64); q1 += __shfl_xor(q1, off, 64);
    }
    if ((tid & 63) == 0) {
        int w6 = tid >> 6;
        red[w6 * 4 + 0] = s0; red[w6 * 4 + 1] = q0;
        red[w6 * 4 + 2] = s1; red[w6 * 4 + 3] = q1;
    }
    __syncthreads();
    if (tid == 0) {
        float S0 = 0.f, Q0 = 0.f, S1 = 0.f, Q1 = 0.f;
#pragma unroll
        for (int w6 = 0; w6 < 4; ++w6) {
            S0 += red[w6 * 4 + 0]; Q0 += red[w6 * 4 + 1];
            S1 += red[w6 * 4 + 2]; Q1 += red[w6 * 4 + 3];
        }
        float* pp = partials + ((size_t)f * 64 + c) * 4;
        pp[0] = S0; pp[1] = Q0; pp[2] = S1; pp[3] = Q1;
    }
}

// ---------------------------------------------------------------- k_gnfin
__global__ __launch_bounds__(128) void k_gnfin(const float* __restrict__ partials,
                                               float2* __restrict__ gs) {
    int i = threadIdx.x;
    int f = i >> 2, g = i & 3;
    const float4* p4 = (const float4*)partials;
    float s = 0.f, q = 0.f;
    if (g < 2) {
        for (int cc = 0; cc < 32; ++cc) {
            float4 p = p4[f * 64 + g * 32 + cc];
            s += p.x; q += p.y;
        }
    } else {
        for (int cc = 0; cc < 32; ++cc) {
            float4 p = p4[f * 64 + (g - 2) * 32 + cc];
            s += p.z; q += p.w;
        }
    }
    float mu = s * (1.0f / 131072.0f);
    float var = q * (1.0f / 131072.0f) - mu * mu;
    gs[i] = make_float2(mu, rsqrtf(var + 1e-5f));
}

// ---------------------------------------------------------------- k_gnapply
__global__ __launch_bounds__(256) void k_gnapply(const unsigned short* __restrict__ u,
                                                 const float2* __restrict__ gs,
                                                 const float* __restrict__ gnw,
                                                 const float* __restrict__ gnb,
                                                 float* __restrict__ out) {
    size_t i8 = (size_t)blockIdx.x * 256 + threadIdx.x;
    u16x8 v = ((const u16x8*)u)[i8];
    int cl = (int)(i8 >> 9);
    int c = cl & 127;
    int fg = cl >> 5;
    float2 ms = gs[fg];
    float sc = ms.y * gnw[c];
    float sh = gnb[c] - ms.x * sc;
    float4 r0, r1;
    r0.x = bf2f(v[0]) * sc + sh; r0.y = bf2f(v[1]) * sc + sh;
    r0.z = bf2f(v[2]) * sc + sh; r0.w = bf2f(v[3]) * sc + sh;
    r1.x = bf2f(v[4]) * sc + sh; r1.y = bf2f(v[5]) * sc + sh;
    r1.z = bf2f(v[6]) * sc + sh; r1.w = bf2f(v[7]) * sc + sh;
    ((float4*)out)[i8 * 2]     = r0;
    ((float4*)out)[i8 * 2 + 1] = r1;
}

// ---------------------------------------------------------------- launch
extern "C" void kernel_launch(void* const* d_in, const int* in_sizes, int n_in,
                              void* d_out, int out_size, void* d_ws, size_t ws_size,
                              hipStream_t stream) {
    (void)in_sizes; (void)n_in; (void)out_size; (void)ws_size;
    const float* x   = (const float*)d_in[0];
    const float* dts = (const float*)d_in[1];
    const float* gw  = (const float*)d_in[2];
    const float* gb  = (const float*)d_in[3];
    const float* cwa = (const float*)d_in[4];
    const float* cwb = (const float*)d_in[5];
    const float* cba = (const float*)d_in[6];
    const float* cbb = (const float*)d_in[7];
    const float* gnw = (const float*)d_in[8];
    const float* gnb = (const float*)d_in[9];
    float* out = (float*)d_out;
    char* ws = (char*)d_ws;

    unsigned*       Sb  = (unsigned*)ws;                       // 34,603,008 B
    unsigned short* Hb  = (unsigned short*)(ws + 34603008);    // 33,554,432 B
    unsigned short* Ub  = (unsigned short*)(ws + 68157440);    // 33,554,432 B
    unsigned short* H1b = (unsigned short*)(ws + 101711872);   // 33,554,432 B
    float*  stats    = (float*)(ws + 135266304);
    float2* A        = (float2*)(ws + 135282688);
    float2* Xt       = (float2*)(ws + 135315456);
    float2* gs       = (float2*)(ws + 135348224);
    float*  partials = (float*)(ws + 135349248);
    unsigned short* Wb = (unsigned short*)ws;                  // aliases Sb (dead after irfft2b)

    k_rfft2s<<<2048, 256, 0, stream>>>(x, Sb, stats);
    k_params<<<16, 256, 0, stream>>>(stats, gw, gb, dts, A, Xt);
    k_scan<<<2112, 256, 0, stream>>>(Sb, A, Xt);
    k_irfft2b<<<2048, 256, 0, stream>>>(Sb, Hb);
    k_wprep<<<576, 256, 0, stream>>>(cwa, cwb, Wb);
    k_conv_mfma<<<dim3(32, 32), 256, 0, stream>>>(Hb, Wb, cba, cbb, Ub);
    k_helm<<<2048, 256, 0, stream>>>(Ub, H1b, partials);
    k_gnfin<<<1, 128, 0, stream>>>(partials, gs);
    k_gnapply<<<8192, 256, 0, stream>>>(H1b, gs, gnw, gnb, out);
}